// Round 5
// baseline (138.907 us; speedup 1.0000x reference)
//
#include <hip/hip_runtime.h>
#include <hip/hip_bf16.h>
#include <stdint.h>
#include <stddef.h>

typedef __bf16 bf16_t;
typedef __bf16 bf16x8 __attribute__((ext_vector_type(8)));
typedef __bf16 bf16x4 __attribute__((ext_vector_type(4)));
typedef float  f32x4  __attribute__((ext_vector_type(4)));

#define NB 8192
#define ND 512
#define NH 2048
#define NHV 512
#define NVO 256
#define RF_TOL 1e-3f
#define NEWTON_MAX 16

typedef const __attribute__((address_space(1))) void gvoid_t;
typedef __attribute__((address_space(3))) void lvoid_t;

__device__ __forceinline__ void gload_lds16(const void* g, void* l) {
  __builtin_amdgcn_global_load_lds((gvoid_t*)g, (lvoid_t*)l, 16, 0, 0);
}

__device__ __forceinline__ float fast_tanhf(float x) {
  x = fminf(fmaxf(x, -15.0f), 15.0f);
  float e = __expf(2.0f * x);
  return (e - 1.0f) * __builtin_amdgcn_rcpf(e + 1.0f);
}

struct GJob {
  const bf16_t* A;    // [8192][K] row-major bf16
  const bf16_t* Bt;   // [N][K] row-major bf16 (pre-transposed B)
  const float*  bias; // [N] or null
  bf16_t* Cbf;        // [8192][N] or null
  float*  Cf;         // [8192][N] or null
  int N, K, nbx, tanh_act;
};

// ======== G1 engine: 256x256 tile, BK=64, dbuf + COUNTED vmcnt (T3/T4) =====
// r4 failure: __launch_bounds__(512,2) forced a 128-VGPR cap (2 waves/SIMD min)
// while the live set is ~200 -> ~100 regs spilled to scratch every K-step
// (VGPR_Count=124, MfmaUtil 13%, 60us). Fix: (512,1) -> 256-VGPR cap (block
// size alone guarantees 2 waves/SIMD), and a low-liveness inner loop: per
// K-half load 4 B-frags, then per-i {1 A-frag ds_read -> 4 MFMA} so peak live
// is acc(128) + bfr(16) + pipelined afr(~12), not a 24-frag burst.
// Schedule per step t (tile t in buf[t%2]):
//   vmcnt(8): my tile-t loads done (tile t+1's 8 stay in flight); barrier
//   {B-frags, per-i A-frag + MFMA} for ks=0,1   (compiler inserts lgkm waits)
//   lgkmcnt(0); barrier  -> buf[t%2] fully read by ALL waves (WAR closed)
//   stage tile t+2 -> buf[t%2]  (8 gload_lds; needed at step t+2's vmcnt)
// Raw s_barrier does NOT drain vmcnt — prefetch spans both barriers.
// XOR swizzle (row,c): byte row*128 + (c ^ ((row&7)<<4)); gload dest LINEAR,
// source pre-swizzled (rule #21).
__global__ __launch_bounds__(512, 1)
void gemm256_kernel(GJob j0, GJob j1)
{
  __shared__ bf16_t As[2 * 256 * 64];   // 64KB (two K-tiles)
  __shared__ bf16_t Bs[2 * 256 * 64];   // 64KB

  // flat id + bijective XCD swizzle (grid total divisible by 8)
  int f = (int)blockIdx.y * (int)gridDim.x + (int)blockIdx.x;
  const int nwg = (int)gridDim.x * (int)gridDim.y;
  f = (f & 7) * (nwg >> 3) + (f >> 3);
  const int bx0 = f % (int)gridDim.x, by = f / (int)gridDim.x;

  const bool first = bx0 < j0.nbx;
  const GJob jb = first ? j0 : j1;
  const int bx = bx0 - (first ? 0 : j0.nbx);
  const int K = jb.K, N = jb.N;

  const int t = threadIdx.x, lane = t & 63, w = t >> 6;
  const int wm = w >> 2, wn = w & 3;          // 2M x 4N wave grid
  const int la = lane & 15, lg = lane >> 4;
  const size_t m0 = (size_t)by * 256, n0 = (size_t)bx * 256;

  // staging: tile = 256 rows x 128B = 32KB/operand; thread covers 4 chunks
  int soff[4];                                 // K<=512 here: fits int
#pragma unroll
  for (int j = 0; j < 4; ++j) {
    const int off = t * 16 + j * 8192;
    const int r = off >> 7, c = off & 127;
    soff[j] = r * K + ((c ^ ((r & 7) << 4)) >> 1);  // pre-swizzled source
  }
  const bf16_t* Ab = jb.A + m0 * K;
  const bf16_t* Bb = jb.Bt + n0 * K;

  // read-side swizzled offsets: base + i*2048 + sw[ks]
  const int swz = (la & 7) << 4;
  const int sw0 = (lg * 16) ^ swz;
  const int sw1 = (64 + lg * 16) ^ swz;
  const int abase = (wm * 128 + la) * 128;
  const int bbase = (wn * 64 + la) * 128;

  f32x4 acc[8][4] = {};
  const int NT = K >> 6;                       // 8 for K=512

  // prologue: stage tiles 0 (buf0) and 1 (buf1); first vmcnt(8) covers tile 0
#pragma unroll
  for (int j = 0; j < 4; ++j) gload_lds16(Ab + soff[j], (char*)As + (t * 16 + j * 8192));
#pragma unroll
  for (int j = 0; j < 4; ++j) gload_lds16(Bb + soff[j], (char*)Bs + (t * 16 + j * 8192));
#pragma unroll
  for (int j = 0; j < 4; ++j) gload_lds16(Ab + soff[j] + 64, (char*)As + 32768 + (t * 16 + j * 8192));
#pragma unroll
  for (int j = 0; j < 4; ++j) gload_lds16(Bb + soff[j] + 64, (char*)Bs + 32768 + (t * 16 + j * 8192));

  for (int ts = 0; ts < NT; ++ts) {
    if (ts < NT - 1) asm volatile("s_waitcnt vmcnt(8)" ::: "memory");
    else             asm volatile("s_waitcnt vmcnt(0)" ::: "memory");
    __builtin_amdgcn_s_barrier();
    asm volatile("" ::: "memory");

    const char* pa = (const char*)As + (ts & 1) * 32768;
    const char* pb = (const char*)Bs + (ts & 1) * 32768;

    // low-liveness compute: per K-half, 4 B-frags resident, A streamed per-i
#pragma unroll
    for (int ks = 0; ks < 2; ++ks) {
      const int sw = ks ? sw1 : sw0;
      bf16x8 bfr[4];
#pragma unroll
      for (int j = 0; j < 4; ++j)
        bfr[j] = *(const bf16x8*)(pb + bbase + j * 2048 + sw);
#pragma unroll
      for (int i = 0; i < 8; ++i) {
        const bf16x8 a = *(const bf16x8*)(pa + abase + i * 2048 + sw);
#pragma unroll
        for (int j = 0; j < 4; ++j)
          acc[i][j] = __builtin_amdgcn_mfma_f32_16x16x32_bf16(a, bfr[j], acc[i][j], 0, 0, 0);
      }
    }
    asm volatile("s_waitcnt lgkmcnt(0)" ::: "memory");
    __builtin_amdgcn_s_barrier();              // buf[ts&1] free for restage
    asm volatile("" ::: "memory");

    if (ts + 2 < NT) {                         // stage tile ts+2 into buf[ts&1]
      const int k0 = (ts + 2) << 6;
      char* da = (char*)As + (ts & 1) * 32768;
      char* db = (char*)Bs + (ts & 1) * 32768;
#pragma unroll
      for (int j = 0; j < 4; ++j) gload_lds16(Ab + soff[j] + k0, da + (t * 16 + j * 8192));
#pragma unroll
      for (int j = 0; j < 4; ++j) gload_lds16(Bb + soff[j] + k0, db + (t * 16 + j * 8192));
    }
  }

  // epilogue
#pragma unroll
  for (int i = 0; i < 8; ++i) {
#pragma unroll
    for (int j = 0; j < 4; ++j) {
      const size_t col = n0 + wn * 64 + j * 16 + la;
      const float bv = jb.bias ? jb.bias[col] : 0.0f;
#pragma unroll
      for (int r = 0; r < 4; ++r) {
        const size_t row = m0 + wm * 128 + i * 16 + lg * 4 + r;
        float v = acc[i][j][r] + bv;
        if (jb.tanh_act) v = fast_tanhf(v);
        if (jb.Cbf) jb.Cbf[row * N + col] = (bf16_t)v;
        if (jb.Cf)  jb.Cf [row * N + col] = v;
      }
    }
  }
}

// ---- narrow-N GEMM: BMx128 tile, BK=64, single-buffer (m97 structure) ------
template<int BM>
__global__ __launch_bounds__(256, 4)
void gemm_kernel(GJob j0, GJob j1)
{
  constexpr int MI = BM / 32;          // A-frags (16-row) per wave half
  __shared__ bf16_t As[BM * 64];       // BM x 128B
  __shared__ bf16_t Bs[128 * 64];      // 16KB
  const bool first = (int)blockIdx.x < j0.nbx;
  const GJob jb = first ? j0 : j1;
  const int bx = (int)blockIdx.x - (first ? 0 : j0.nbx);
  const int K = jb.K, N = jb.N;

  const int t = threadIdx.x, lane = t & 63, w = t >> 6;
  const int wm = w >> 1, wn = w & 1;
  const int la = lane & 15, lg = lane >> 4;
  const size_t m0 = (size_t)blockIdx.y * BM, n0 = (size_t)bx * 128;

  size_t soffA[MI], soffB[4]; int doff[4];
#pragma unroll
  for (int j = 0; j < 4; ++j) {
    const int off = t * 16 + j * 4096;
    const int r = off >> 7, c = off & 127;
    const size_t so = (size_t)r * K + ((c ^ ((r & 7) << 4)) >> 1);  // pre-swizzled
    if (j < MI) soffA[j] = so;
    soffB[j] = so;
    doff[j] = off;
  }
  const bf16_t* Ab = jb.A + m0 * K;
  const bf16_t* Bb = jb.Bt + n0 * K;

  int abyte[MI][2], bbyte[4][2];
#pragma unroll
  for (int ks = 0; ks < 2; ++ks) {
#pragma unroll
    for (int i = 0; i < MI; ++i) {
      const int ra = wm * (BM / 2) + i * 16 + la;
      abyte[i][ks] = ra * 128 + ((ks * 64 + lg * 16) ^ ((ra & 7) << 4));
    }
#pragma unroll
    for (int j = 0; j < 4; ++j) {
      const int rb = wn * 64 + j * 16 + la;
      bbyte[j][ks] = rb * 128 + ((ks * 64 + lg * 16) ^ ((rb & 7) << 4));
    }
  }

  f32x4 acc[MI][4] = {};
  const int nsteps = K >> 6;

  for (int ts = 0; ts < nsteps; ++ts) {
    const int k0 = ts << 6;
#pragma unroll
    for (int j = 0; j < MI; ++j)
      gload_lds16(Ab + soffA[j] + k0, (char*)As + doff[j]);
#pragma unroll
    for (int j = 0; j < 4; ++j)
      gload_lds16(Bb + soffB[j] + k0, (char*)Bs + doff[j]);
    __syncthreads();

    bf16x8 afr[MI][2], bfr[4][2];
#pragma unroll
    for (int ks = 0; ks < 2; ++ks) {
#pragma unroll
      for (int i = 0; i < MI; ++i)
        afr[i][ks] = *(const bf16x8*)((const char*)As + abyte[i][ks]);
#pragma unroll
      for (int j = 0; j < 4; ++j)
        bfr[j][ks] = *(const bf16x8*)((const char*)Bs + bbyte[j][ks]);
    }
#pragma unroll
    for (int ks = 0; ks < 2; ++ks)
#pragma unroll
      for (int i = 0; i < MI; ++i)
#pragma unroll
        for (int j = 0; j < 4; ++j)
          acc[i][j] = __builtin_amdgcn_mfma_f32_16x16x32_bf16(afr[i][ks], bfr[j][ks], acc[i][j], 0, 0, 0);
    __syncthreads();
  }

#pragma unroll
  for (int i = 0; i < MI; ++i) {
#pragma unroll
    for (int j = 0; j < 4; ++j) {
      const size_t col = n0 + wn * 64 + j * 16 + la;
      const float bv = jb.bias ? jb.bias[col] : 0.0f;
#pragma unroll
      for (int r = 0; r < 4; ++r) {
        const size_t row = m0 + wm * (BM / 2) + i * 16 + lg * 4 + r;
        float v = acc[i][j][r] + bv;
        if (jb.tanh_act) v = fast_tanhf(v);
        if (jb.Cbf) jb.Cbf[row * N + col] = (bf16_t)v;
        if (jb.Cf)  jb.Cf [row * N + col] = v;
      }
    }
  }
}

// ------------------ fused prep: 4 transposes + rowcast(x) -------------------
__device__ __forceinline__ void tr_body(const float* __restrict__ src, bf16_t* __restrict__ dst,
                                        int R, int C, int bidx, float (*tile)[33]) {
  const int tilesx = C >> 5;
  const int bi = (bidx / tilesx) << 5, bj = (bidx % tilesx) << 5;
  const int t = threadIdx.x, tx = t & 31, ty = t >> 5;
#pragma unroll
  for (int r = ty; r < 32; r += 8)
    tile[r][tx] = src[(size_t)(bi + r) * C + (bj + tx)];
  __syncthreads();
#pragma unroll
  for (int r = ty; r < 32; r += 8)
    dst[(size_t)(bj + r) * R + (bi + tx)] = (bf16_t)tile[tx][r];
}

__global__ void prep_kernel(const float* __restrict__ x, bf16_t* __restrict__ xbf, float* __restrict__ xsq,
                            const float* __restrict__ W1, bf16_t* __restrict__ w1t,
                            const float* __restrict__ W2, bf16_t* __restrict__ w2t,
                            const float* __restrict__ Wv1, bf16_t* __restrict__ wv1t,
                            const float* __restrict__ Wv2, bf16_t* __restrict__ wv2t)
{
  __shared__ float tile[32][33];
  const int b = blockIdx.x;
  if (b < 1024)      tr_body(W1, w1t, 512, 2048, b, tile);
  else if (b < 2048) tr_body(W2, w2t, 2048, 512, b - 1024, tile);
  else if (b < 2304) tr_body(Wv1, wv1t, 512, 512, b - 2048, tile);
  else if (b < 2432) tr_body(Wv2, wv2t, 512, 256, b - 2304, tile);
  else {
    const int t = threadIdx.x;
    const int row = (b - 2432) * 4 + (t >> 6), l = t & 63;
    const float4* sr = (const float4*)(x + (size_t)row * ND);
    bf16x4* dw = (bf16x4*)(xbf + (size_t)row * ND);
    float s = 0.0f;
#pragma unroll
    for (int c = l; c < ND / 4; c += 64) {
      float4 v = sr[c];
      s = fmaf(v.x, v.x, fmaf(v.y, v.y, fmaf(v.z, v.z, fmaf(v.w, v.w, s))));
      bf16x4 o;
      o[0] = (bf16_t)v.x; o[1] = (bf16_t)v.y; o[2] = (bf16_t)v.z; o[3] = (bf16_t)v.w;
      dw[c] = o;
    }
#pragma unroll
    for (int m = 32; m; m >>= 1) s += __shfl_xor(s, m);
    if (l == 0) xsq[row] = s;
  }
}

// --------- fused post: fsq = sumsq(fbf row), tgt = 0.99*(sumsq(yx)+0.01 xsq)
__global__ void post_kernel(const bf16_t* __restrict__ fbf, const float* __restrict__ yx,
                            const float* __restrict__ xsq,
                            float* __restrict__ fsq, float* __restrict__ tgt)
{
  const int b = blockIdx.x, t = threadIdx.x, l = t & 63;
  if (t < 64) {
    bf16x8 v = *(const bf16x8*)(fbf + (size_t)b * ND + l * 8);
    float s = 0.0f;
#pragma unroll
    for (int q = 0; q < 8; ++q) { float f = (float)v[q]; s = fmaf(f, f, s); }
#pragma unroll
    for (int m = 32; m; m >>= 1) s += __shfl_xor(s, m);
    if (l == 0) fsq[b] = s;
  } else {
    float4 v = ((const float4*)(yx + (size_t)b * NVO))[l];
    float s = fmaf(v.x, v.x, fmaf(v.y, v.y, fmaf(v.z, v.z, v.w * v.w)));
#pragma unroll
    for (int m = 32; m; m >>= 1) s += __shfl_xor(s, m);
    if (l == 0) tgt[b] = 0.99f * (s + 0.01f * xsq[b]);
  }
}

// --------------------------- Newton root-find -------------------------------
__global__ __launch_bounds__(512, 2)
void newton_kernel(const bf16_t* __restrict__ u0, const bf16_t* __restrict__ Wv2t,
                   const float* __restrict__ fsq, const float* __restrict__ tgt,
                   const float* __restrict__ fhat, float* __restrict__ out)
{
  __shared__ alignas(16) bf16_t hs[32 * 512];   // 32KB, XOR-swizzled
  __shared__ alignas(16) bf16_t es[32 * 512];
  __shared__ float red[8][32][2];
  __shared__ float alpha_s[32], fsq_s[32], tgt_s[32];
  __shared__ int notdone_s;

  const int t = threadIdx.x, lane = t & 63, w = t >> 6;
  const int la = lane & 15, lg = lane >> 4;
  const int s_base = blockIdx.x * 32;
  const int arow = lane & 31, ahi = lane >> 5;

  bf16x8 bfr[2][16];
#pragma unroll
  for (int nt = 0; nt < 2; ++nt) {
    const bf16_t* bp = Wv2t + (size_t)(w * 32 + nt * 16 + la) * NHV + lg * 8;
#pragma unroll
    for (int k = 0; k < 16; ++k)
      bfr[nt][k] = *(const bf16x8*)(bp + k * 32);
  }

  bf16x8 ureg[4];
#pragma unroll
  for (int i = 0; i < 4; ++i)
    ureg[i] = *(const bf16x8*)(u0 + (size_t)(s_base + arow) * NHV + (w * 8 + ahi * 4 + i) * 8);

  if (t < 32) {
    alpha_s[t] = 1.0f;
    fsq_s[t] = fsq[s_base + t];
    tgt_s[t] = tgt[s_base + t];
  }
  __syncthreads();

  for (int it = 0; it < NEWTON_MAX; ++it) {
    {
      const float c2 = 2.0f * alpha_s[arow];
#pragma unroll
      for (int i = 0; i < 4; ++i) {
        const int k8 = w * 8 + ahi * 4 + i;
        const int byte = (arow << 10) + ((k8 ^ (arow & 7)) << 4);
        bf16x8 uv = ureg[i], hf, ef;
#pragma unroll
        for (int q = 0; q < 8; ++q) {
          float u = (float)uv[q];
          float e = __expf(c2 * u);
          float h = (e - 1.0f) * __builtin_amdgcn_rcpf(e + 1.0f);
          hf[q] = (bf16_t)h;
          ef[q] = (bf16_t)(u * (1.0f - h * h));
        }
        *(bf16x8*)((char*)hs + byte) = hf;
        *(bf16x8*)((char*)es + byte) = ef;
      }
    }
    __syncthreads();

    f32x4 accy[2][2] = {};
    f32x4 accw[2][2] = {};
#pragma unroll
    for (int k = 0; k < 16; ++k) {
#pragma unroll
      for (int mt = 0; mt < 2; ++mt) {
        const int row = mt * 16 + la;
        const int byte = (row << 10) + (((k * 4 + lg) ^ (row & 7)) << 4);
        bf16x8 hf = *(const bf16x8*)((const char*)hs + byte);
        bf16x8 ef = *(const bf16x8*)((const char*)es + byte);
#pragma unroll
        for (int nt = 0; nt < 2; ++nt) {
          accy[mt][nt] = __builtin_amdgcn_mfma_f32_16x16x32_bf16(hf, bfr[nt][k], accy[mt][nt], 0, 0, 0);
          accw[mt][nt] = __builtin_amdgcn_mfma_f32_16x16x32_bf16(ef, bfr[nt][k], accw[mt][nt], 0, 0, 0);
        }
      }
    }

#pragma unroll
    for (int mt = 0; mt < 2; ++mt) {
#pragma unroll
      for (int r = 0; r < 4; ++r) {
        float sy = 0.0f, sw = 0.0f;
#pragma unroll
        for (int nt = 0; nt < 2; ++nt) {
          float yv = accy[mt][nt][r], wv = accw[mt][nt][r];
          sy = fmaf(yv, yv, sy);
          sw = fmaf(yv, wv, sw);
        }
        sy += __shfl_xor(sy, 1); sw += __shfl_xor(sw, 1);
        sy += __shfl_xor(sy, 2); sw += __shfl_xor(sw, 2);
        sy += __shfl_xor(sy, 4); sw += __shfl_xor(sw, 4);
        sy += __shfl_xor(sy, 8); sw += __shfl_xor(sw, 8);
        if (la == 0) {
          red[w][mt * 16 + lg * 4 + r][0] = sy;
          red[w][mt * 16 + lg * 4 + r][1] = sw;
        }
      }
    }
    __syncthreads();
    if (t < 32) {
      float SY = 0.0f, SW = 0.0f;
#pragma unroll
      for (int w8 = 0; w8 < 8; ++w8) {
        SY += red[w8][t][0];
        SW += red[w8][t][1];
      }
      float a = alpha_s[t];
      const float fs = fsq_s[t];
      const float V = SY + 0.01f * a * a * fs;
      const float dV = 2.0f * SW + 0.02f * a * fs;
      const float resid = V - tgt_s[t];
      const bool go = resid > RF_TOL;
      if (go) alpha_s[t] = a - resid / dV;
      const int nd = __any(go);
      if (t == 0) notdone_s = nd;
    }
    __syncthreads();
    if (!notdone_s) break;
  }

  {
    const int r = t >> 4;
    const int c4 = t & 15;
    const float a = alpha_s[r];
    const size_t rb = (size_t)(s_base + r) * ND;
    const float4* sp = (const float4*)(fhat + rb);
    float4* dp = (float4*)(out + rb);
#pragma unroll
    for (int jj = 0; jj < 8; ++jj) {
      float4 v = sp[c4 + jj * 16];
      v.x *= a; v.y *= a; v.z *= a; v.w *= a;
      dp[c4 + jj * 16] = v;
    }
  }
}

extern "C" void kernel_launch(void* const* d_in, const int* in_sizes, int n_in,
                              void* d_out, int out_size, void* d_ws, size_t ws_size,
                              hipStream_t stream)
{
  (void)in_sizes; (void)n_in; (void)out_size; (void)ws_size;
  const float* x   = (const float*)d_in[0];
  const float* W1  = (const float*)d_in[1];
  const float* b1  = (const float*)d_in[2];
  const float* W2  = (const float*)d_in[3];
  const float* b2  = (const float*)d_in[4];
  const float* Wv1 = (const float*)d_in[5];
  const float* Wv2 = (const float*)d_in[6];
  float* out = (float*)d_out;

  char* ws = (char*)d_ws;
  size_t off = 0;
  auto alloc = [&](size_t n) { char* p = ws + off; off += (n + 255) & ~(size_t)255; return p; };

  bf16_t* xbf  = (bf16_t*)alloc((size_t)NB * ND * 2);
  bf16_t* w1t  = (bf16_t*)alloc((size_t)NH * ND * 2);
  bf16_t* w2t  = (bf16_t*)alloc((size_t)ND * NH * 2);
  bf16_t* wv1t = (bf16_t*)alloc((size_t)NHV * ND * 2);
  bf16_t* wv2t = (bf16_t*)alloc((size_t)NVO * NHV * 2);
  bf16_t* h1   = (bf16_t*)alloc((size_t)NB * NH * 2);
  float*  fhat = (float*)alloc((size_t)NB * ND * 4);
  bf16_t* fbf  = (bf16_t*)alloc((size_t)NB * ND * 2);
  bf16_t* hx   = (bf16_t*)alloc((size_t)NB * NHV * 2);
  float*  yx   = (float*)alloc((size_t)NB * NVO * 4);
  bf16_t* u0bf = (bf16_t*)alloc((size_t)NB * NHV * 2);
  float*  xsq  = (float*)alloc((size_t)NB * 4);
  float*  fsq  = (float*)alloc((size_t)NB * 4);
  float*  tgt  = (float*)alloc((size_t)NB * 4);

  // 1. fused prep: W1,W2,Wv1,Wv2 transpose+cast (2432 blocks) + x rowcast (2048)
  prep_kernel<<<4480, 256, 0, stream>>>(x, xbf, xsq, W1, w1t, W2, w2t, Wv1, wv1t, Wv2, wv2t);

  // 2. G1: h1 = tanh(x@W1+b1) [8 bx] + hx = tanh(x@Wv1) [2 bx]
  //    256^2 deep-pipe: 10x32 = 320 blocks, 1 block/CU, counted vmcnt
  GJob jh1 { xbf, w1t,  b1,      h1,  nullptr, NH,  ND, NH  / 256, 1 };
  GJob jhx { xbf, wv1t, nullptr, hx,  nullptr, NHV, ND, NHV / 256, 1 };
  gemm256_kernel<<<dim3(NH / 256 + NHV / 256, NB / 256), 512, 0, stream>>>(jh1, jhx);

  // 3. G2: fhat = h1@W2+b2 (f32 + bf16 outputs) + yx = hx@Wv2
  //    BM=64: 6x128 = 768 blocks (3/CU)
  GJob jf  { h1,  w2t,  b2,      fbf, fhat,    ND,  NH, ND  / 128, 0 };
  GJob jy  { hx,  wv2t, nullptr, nullptr, yx,  NVO, NHV, NVO / 128, 0 };
  gemm_kernel<64><<<dim3(ND / 128 + NVO / 128, NB / 64), 256, 0, stream>>>(jf, jy);

  // 4. fused post: fsq (from fbf) + target (from yx, xsq)
  post_kernel<<<NB, 128, 0, stream>>>(fbf, yx, xsq, fsq, tgt);

  // 5. G3: u0 = fbf @ Wv1 (bf16 output — newton casts to bf16 anyway)
  GJob ju  { fbf, wv1t, nullptr, u0bf, nullptr, NHV, ND, NHV / 128, 0 };
  gemm_kernel<64><<<dim3(NHV / 128, NB / 64), 256, 0, stream>>>(ju, ju);

  // 6. per-sample masked Newton + fused out = fhat * alpha
  newton_kernel<<<NB / 32, 512, 0, stream>>>(u0bf, wv2t, fsq, tgt, fhat, out);
}

// Round 6
// 132.882 us; speedup vs baseline: 1.0453x; 1.0453x over previous
//
#include <hip/hip_runtime.h>
#include <hip/hip_bf16.h>
#include <stdint.h>
#include <stddef.h>

typedef __bf16 bf16_t;
typedef __bf16 bf16x8 __attribute__((ext_vector_type(8)));
typedef __bf16 bf16x4 __attribute__((ext_vector_type(4)));
typedef float  f32x4  __attribute__((ext_vector_type(4)));

#define NB 8192
#define ND 512
#define NH 2048
#define NHV 512
#define NVO 256
#define RF_TOL 1e-3f
#define NEWTON_MAX 16

typedef const __attribute__((address_space(1))) void gvoid_t;
typedef __attribute__((address_space(3))) void lvoid_t;

__device__ __forceinline__ void gload_lds16(const void* g, void* l) {
  __builtin_amdgcn_global_load_lds((gvoid_t*)g, (lvoid_t*)l, 16, 0, 0);
}

__device__ __forceinline__ float fast_tanhf(float x) {
  x = fminf(fmaxf(x, -15.0f), 15.0f);
  float e = __expf(2.0f * x);
  return (e - 1.0f) * __builtin_amdgcn_rcpf(e + 1.0f);
}

struct GJob {
  const bf16_t* A;    // [8192][K] row-major bf16
  const bf16_t* Bt;   // [N][K] row-major bf16 (pre-transposed B)
  const float*  bias; // [N] or null
  bf16_t* Cbf;        // [8192][N] or null
  float*  Cf;         // [8192][N] or null
  int N, K, nbx, tanh_act;
};

// ======== G1 engine: 256x128 tile, BK=64, TRI-buffer counted-vmcnt ==========
// Why tri-buffer: with 2 bufs, the stage->use distance is one group and the
// group-end wait is forced to vmcnt(0) (r1/r5 nulls). With 3 bufs, tile kt
// lives in buf kt%3; tile kt+2 is staged DURING group kt into the buf freed
// at group kt-1's end -> loads span 2 groups, group-end wait = vmcnt(6).
// Group kt = 2 fine phases (m196: fine interleave is the lever):
//  ph0: read B(4)+A-quad0(8) of tile kt | stageA(kt+2) | lgkm(8) | bar |
//       lgkm(0) | setprio1 | 16 MFMA | setprio0 | bar
//  ph1: read A-quad1(8)                | stageB(kt+2) | vmcnt(6) | bar |
//       lgkm(0) | setprio1 | 16 MFMA | setprio0 | bar
// vmcnt ledger (2 loads/B-half, 4/A): at ph1's vmcnt(6), outstanding =
//   tile kt+1 {A4,B2} (issued grp kt-1) + tile kt+2 {A4,B2} (this grp) = 12
//   -> wait to 6 => tile kt+1 fully staged before grp kt+1 reads it. Tail:
//   kt=NT-2 -> vmcnt(0) (no new issues); kt=NT-1 -> none.
// WAR: stage into buf (kt+2)%3 (= tile kt-1's buf) issues after grp kt-1's
//   trailing barrier, which followed every wave's lgkmcnt(0) on its reads.
// XOR swizzle (row,c): byte row*128 + (c ^ ((row&7)<<4)); gload dest LINEAR,
// source pre-swizzled (rule #21). LDS = 3 x 48KB (A0,A1,B) = 144KB.
__global__ __launch_bounds__(512, 1)
void gemm_tri_kernel(GJob j0, GJob j1)
{
  __shared__ bf16_t lds3[3 * 24576];   // 144KB

  // flat id + bijective XCD swizzle (grid total divisible by 8)
  int f = (int)blockIdx.y * (int)gridDim.x + (int)blockIdx.x;
  const int nwg = (int)gridDim.x * (int)gridDim.y;
  f = (f & 7) * (nwg >> 3) + (f >> 3);
  const int bx0 = f % (int)gridDim.x, by = f / (int)gridDim.x;

  const bool first = bx0 < j0.nbx;
  const GJob jb = first ? j0 : j1;
  const int bx = bx0 - (first ? 0 : j0.nbx);
  const int K = jb.K, N = jb.N;

  const int t = threadIdx.x, lane = t & 63, w = t >> 6;
  const int wm = w >> 2, wn = w & 3;          // 2M x 4N waves; wave out 128x32
  const int la = lane & 15, lg = lane >> 4;
  const size_t m0 = (size_t)by * 256, n0 = (size_t)bx * 128;

  const bf16_t* Ab = jb.A + m0 * K;
  const bf16_t* Bb = jb.Bt + n0 * K;
  char* ldsB = (char*)lds3;

  // staging: half-tile = 128 rows x 128B = 16KB; thread covers 2 x 16B
  const int r0 = t >> 3;                                   // 0..63
  const int swc = (((t & 7) * 16) ^ ((r0 & 7) << 4)) >> 1; // elems, 16B-aligned
  const int sA0 = r0 * K + swc;

  // read-side swizzled offsets
  const int swz = (la & 7) << 4;
  const int sw0 = (lg * 16) ^ swz;
  const int sw1 = (64 + lg * 16) ^ swz;
  const int abase = wm * 16384 + la * 128;          // + i*2048 + sw
  const int bbase = 32768 + (wn * 32 + la) * 128;   // + j*2048 + sw

  f32x4 acc[8][2] = {};
  const int NT = K >> 6;                            // 8 for K=512

#define STAGE_A(kt_) do { \
    char* dA = ldsB + ((kt_) % 3) * 49152; \
    const int ko = (kt_) << 6; \
    gload_lds16(Ab + sA0 + ko,               dA + t * 16); \
    gload_lds16(Ab + sA0 + 64 * K + ko,      dA + t * 16 + 8192); \
    gload_lds16(Ab + 128 * K + sA0 + ko,     dA + 16384 + t * 16); \
    gload_lds16(Ab + 192 * K + sA0 + ko,     dA + 16384 + t * 16 + 8192); \
  } while (0)
#define STAGE_B(kt_) do { \
    char* dB = ldsB + ((kt_) % 3) * 49152 + 32768; \
    const int ko = (kt_) << 6; \
    gload_lds16(Bb + sA0 + ko,               dB + t * 16); \
    gload_lds16(Bb + sA0 + 64 * K + ko,      dB + t * 16 + 8192); \
  } while (0)

  // prologue: tiles 0 and 1 (bufs 0,1); vmcnt(6) -> tile 0 staged
  STAGE_A(0); STAGE_B(0);
  STAGE_A(1); STAGE_B(1);
  asm volatile("s_waitcnt vmcnt(6)" ::: "memory");
  __builtin_amdgcn_s_barrier();
  asm volatile("" ::: "memory");

  for (int kt = 0; kt < NT; ++kt) {
    const char* pb = ldsB + (kt % 3) * 49152;
    const bool st = (kt + 2 < NT);

    // ---------------- phase 0: B + A-quad0, stage A(kt+2) ----------------
    bf16x8 bfr[2][2], afr[4][2];
#pragma unroll
    for (int j = 0; j < 2; ++j) {
      bfr[j][0] = *(const bf16x8*)(pb + bbase + j * 2048 + sw0);
      bfr[j][1] = *(const bf16x8*)(pb + bbase + j * 2048 + sw1);
    }
#pragma unroll
    for (int i = 0; i < 4; ++i) {
      afr[i][0] = *(const bf16x8*)(pb + abase + i * 2048 + sw0);
      afr[i][1] = *(const bf16x8*)(pb + abase + i * 2048 + sw1);
    }
    if (st) STAGE_A(kt + 2);
    asm volatile("s_waitcnt lgkmcnt(8)" ::: "memory");
    __builtin_amdgcn_s_barrier();
    asm volatile("s_waitcnt lgkmcnt(0)" ::: "memory");
    __builtin_amdgcn_s_setprio(1);
#pragma unroll
    for (int ks = 0; ks < 2; ++ks)
#pragma unroll
      for (int i = 0; i < 4; ++i)
#pragma unroll
        for (int j = 0; j < 2; ++j)
          acc[i][j] = __builtin_amdgcn_mfma_f32_16x16x32_bf16(afr[i][ks], bfr[j][ks], acc[i][j], 0, 0, 0);
    __builtin_amdgcn_s_setprio(0);
    __builtin_amdgcn_s_barrier();
    asm volatile("" ::: "memory");

    // ---------------- phase 1: A-quad1, stage B(kt+2), group vmcnt --------
    bf16x8 af2[4][2];
#pragma unroll
    for (int i = 0; i < 4; ++i) {
      af2[i][0] = *(const bf16x8*)(pb + abase + (i + 4) * 2048 + sw0);
      af2[i][1] = *(const bf16x8*)(pb + abase + (i + 4) * 2048 + sw1);
    }
    if (st) STAGE_B(kt + 2);
    if (st)                asm volatile("s_waitcnt vmcnt(6)" ::: "memory");
    else if (kt + 1 < NT)  asm volatile("s_waitcnt vmcnt(0)" ::: "memory");
    __builtin_amdgcn_s_barrier();
    asm volatile("s_waitcnt lgkmcnt(0)" ::: "memory");
    __builtin_amdgcn_s_setprio(1);
#pragma unroll
    for (int ks = 0; ks < 2; ++ks)
#pragma unroll
      for (int i = 0; i < 4; ++i)
#pragma unroll
        for (int j = 0; j < 2; ++j)
          acc[i + 4][j] = __builtin_amdgcn_mfma_f32_16x16x32_bf16(af2[i][ks], bfr[j][ks], acc[i + 4][j], 0, 0, 0);
    __builtin_amdgcn_s_setprio(0);
    __builtin_amdgcn_s_barrier();
    asm volatile("" ::: "memory");
  }
#undef STAGE_A
#undef STAGE_B

  // epilogue
#pragma unroll
  for (int i = 0; i < 8; ++i) {
#pragma unroll
    for (int j = 0; j < 2; ++j) {
      const size_t col = n0 + wn * 32 + j * 16 + la;
      const float bv = jb.bias ? jb.bias[col] : 0.0f;
#pragma unroll
      for (int r = 0; r < 4; ++r) {
        const size_t row = m0 + wm * 128 + i * 16 + lg * 4 + r;
        float v = acc[i][j][r] + bv;
        if (jb.tanh_act) v = fast_tanhf(v);
        if (jb.Cbf) jb.Cbf[row * N + col] = (bf16_t)v;
        if (jb.Cf)  jb.Cf [row * N + col] = v;
      }
    }
  }
}

// ---- narrow-N GEMM: BMx128 tile, BK=64, single-buffer (m97 structure) ------
template<int BM>
__global__ __launch_bounds__(256, 4)
void gemm_kernel(GJob j0, GJob j1)
{
  constexpr int MI = BM / 32;          // A-frags (16-row) per wave half
  __shared__ bf16_t As[BM * 64];       // BM x 128B
  __shared__ bf16_t Bs[128 * 64];      // 16KB
  const bool first = (int)blockIdx.x < j0.nbx;
  const GJob jb = first ? j0 : j1;
  const int bx = (int)blockIdx.x - (first ? 0 : j0.nbx);
  const int K = jb.K, N = jb.N;

  const int t = threadIdx.x, lane = t & 63, w = t >> 6;
  const int wm = w >> 1, wn = w & 1;
  const int la = lane & 15, lg = lane >> 4;
  const size_t m0 = (size_t)blockIdx.y * BM, n0 = (size_t)bx * 128;

  size_t soffA[MI], soffB[4]; int doff[4];
#pragma unroll
  for (int j = 0; j < 4; ++j) {
    const int off = t * 16 + j * 4096;
    const int r = off >> 7, c = off & 127;
    const size_t so = (size_t)r * K + ((c ^ ((r & 7) << 4)) >> 1);  // pre-swizzled
    if (j < MI) soffA[j] = so;
    soffB[j] = so;
    doff[j] = off;
  }
  const bf16_t* Ab = jb.A + m0 * K;
  const bf16_t* Bb = jb.Bt + n0 * K;

  int abyte[MI][2], bbyte[4][2];
#pragma unroll
  for (int ks = 0; ks < 2; ++ks) {
#pragma unroll
    for (int i = 0; i < MI; ++i) {
      const int ra = wm * (BM / 2) + i * 16 + la;
      abyte[i][ks] = ra * 128 + ((ks * 64 + lg * 16) ^ ((ra & 7) << 4));
    }
#pragma unroll
    for (int j = 0; j < 4; ++j) {
      const int rb = wn * 64 + j * 16 + la;
      bbyte[j][ks] = rb * 128 + ((ks * 64 + lg * 16) ^ ((rb & 7) << 4));
    }
  }

  f32x4 acc[MI][4] = {};
  const int nsteps = K >> 6;

  for (int ts = 0; ts < nsteps; ++ts) {
    const int k0 = ts << 6;
#pragma unroll
    for (int j = 0; j < MI; ++j)
      gload_lds16(Ab + soffA[j] + k0, (char*)As + doff[j]);
#pragma unroll
    for (int j = 0; j < 4; ++j)
      gload_lds16(Bb + soffB[j] + k0, (char*)Bs + doff[j]);
    __syncthreads();

    bf16x8 afr[MI][2], bfr[4][2];
#pragma unroll
    for (int ks = 0; ks < 2; ++ks) {
#pragma unroll
      for (int i = 0; i < MI; ++i)
        afr[i][ks] = *(const bf16x8*)((const char*)As + abyte[i][ks]);
#pragma unroll
      for (int j = 0; j < 4; ++j)
        bfr[j][ks] = *(const bf16x8*)((const char*)Bs + bbyte[j][ks]);
    }
#pragma unroll
    for (int ks = 0; ks < 2; ++ks)
#pragma unroll
      for (int i = 0; i < MI; ++i)
#pragma unroll
        for (int j = 0; j < 4; ++j)
          acc[i][j] = __builtin_amdgcn_mfma_f32_16x16x32_bf16(afr[i][ks], bfr[j][ks], acc[i][j], 0, 0, 0);
    __syncthreads();
  }

#pragma unroll
  for (int i = 0; i < MI; ++i) {
#pragma unroll
    for (int j = 0; j < 4; ++j) {
      const size_t col = n0 + wn * 64 + j * 16 + la;
      const float bv = jb.bias ? jb.bias[col] : 0.0f;
#pragma unroll
      for (int r = 0; r < 4; ++r) {
        const size_t row = m0 + wm * (BM / 2) + i * 16 + lg * 4 + r;
        float v = acc[i][j][r] + bv;
        if (jb.tanh_act) v = fast_tanhf(v);
        if (jb.Cbf) jb.Cbf[row * N + col] = (bf16_t)v;
        if (jb.Cf)  jb.Cf [row * N + col] = v;
      }
    }
  }
}

// ------------------ fused prep: 4 transposes + rowcast(x) -------------------
__device__ __forceinline__ void tr_body(const float* __restrict__ src, bf16_t* __restrict__ dst,
                                        int R, int C, int bidx, float (*tile)[33]) {
  const int tilesx = C >> 5;
  const int bi = (bidx / tilesx) << 5, bj = (bidx % tilesx) << 5;
  const int t = threadIdx.x, tx = t & 31, ty = t >> 5;
#pragma unroll
  for (int r = ty; r < 32; r += 8)
    tile[r][tx] = src[(size_t)(bi + r) * C + (bj + tx)];
  __syncthreads();
#pragma unroll
  for (int r = ty; r < 32; r += 8)
    dst[(size_t)(bj + r) * R + (bi + tx)] = (bf16_t)tile[tx][r];
}

__global__ void prep_kernel(const float* __restrict__ x, bf16_t* __restrict__ xbf, float* __restrict__ xsq,
                            const float* __restrict__ W1, bf16_t* __restrict__ w1t,
                            const float* __restrict__ W2, bf16_t* __restrict__ w2t,
                            const float* __restrict__ Wv1, bf16_t* __restrict__ wv1t,
                            const float* __restrict__ Wv2, bf16_t* __restrict__ wv2t)
{
  __shared__ float tile[32][33];
  const int b = blockIdx.x;
  if (b < 1024)      tr_body(W1, w1t, 512, 2048, b, tile);
  else if (b < 2048) tr_body(W2, w2t, 2048, 512, b - 1024, tile);
  else if (b < 2304) tr_body(Wv1, wv1t, 512, 512, b - 2048, tile);
  else if (b < 2432) tr_body(Wv2, wv2t, 512, 256, b - 2304, tile);
  else {
    const int t = threadIdx.x;
    const int row = (b - 2432) * 4 + (t >> 6), l = t & 63;
    const float4* sr = (const float4*)(x + (size_t)row * ND);
    bf16x4* dw = (bf16x4*)(xbf + (size_t)row * ND);
    float s = 0.0f;
#pragma unroll
    for (int c = l; c < ND / 4; c += 64) {
      float4 v = sr[c];
      s = fmaf(v.x, v.x, fmaf(v.y, v.y, fmaf(v.z, v.z, fmaf(v.w, v.w, s))));
      bf16x4 o;
      o[0] = (bf16_t)v.x; o[1] = (bf16_t)v.y; o[2] = (bf16_t)v.z; o[3] = (bf16_t)v.w;
      dw[c] = o;
    }
#pragma unroll
    for (int m = 32; m; m >>= 1) s += __shfl_xor(s, m);
    if (l == 0) xsq[row] = s;
  }
}

// --------- fused post: fsq = sumsq(fbf row), tgt = 0.99*(sumsq(yx)+0.01 xsq)
__global__ void post_kernel(const bf16_t* __restrict__ fbf, const float* __restrict__ yx,
                            const float* __restrict__ xsq,
                            float* __restrict__ fsq, float* __restrict__ tgt)
{
  const int b = blockIdx.x, t = threadIdx.x, l = t & 63;
  if (t < 64) {
    bf16x8 v = *(const bf16x8*)(fbf + (size_t)b * ND + l * 8);
    float s = 0.0f;
#pragma unroll
    for (int q = 0; q < 8; ++q) { float f = (float)v[q]; s = fmaf(f, f, s); }
#pragma unroll
    for (int m = 32; m; m >>= 1) s += __shfl_xor(s, m);
    if (l == 0) fsq[b] = s;
  } else {
    float4 v = ((const float4*)(yx + (size_t)b * NVO))[l];
    float s = fmaf(v.x, v.x, fmaf(v.y, v.y, fmaf(v.z, v.z, v.w * v.w)));
#pragma unroll
    for (int m = 32; m; m >>= 1) s += __shfl_xor(s, m);
    if (l == 0) tgt[b] = 0.99f * (s + 0.01f * xsq[b]);
  }
}

// --------------------------- Newton root-find -------------------------------
__global__ __launch_bounds__(512, 2)
void newton_kernel(const bf16_t* __restrict__ u0, const bf16_t* __restrict__ Wv2t,
                   const float* __restrict__ fsq, const float* __restrict__ tgt,
                   const float* __restrict__ fhat, float* __restrict__ out)
{
  __shared__ alignas(16) bf16_t hs[32 * 512];   // 32KB, XOR-swizzled
  __shared__ alignas(16) bf16_t es[32 * 512];
  __shared__ float red[8][32][2];
  __shared__ float alpha_s[32], fsq_s[32], tgt_s[32];
  __shared__ int notdone_s;

  const int t = threadIdx.x, lane = t & 63, w = t >> 6;
  const int la = lane & 15, lg = lane >> 4;
  const int s_base = blockIdx.x * 32;
  const int arow = lane & 31, ahi = lane >> 5;

  bf16x8 bfr[2][16];
#pragma unroll
  for (int nt = 0; nt < 2; ++nt) {
    const bf16_t* bp = Wv2t + (size_t)(w * 32 + nt * 16 + la) * NHV + lg * 8;
#pragma unroll
    for (int k = 0; k < 16; ++k)
      bfr[nt][k] = *(const bf16x8*)(bp + k * 32);
  }

  bf16x8 ureg[4];
#pragma unroll
  for (int i = 0; i < 4; ++i)
    ureg[i] = *(const bf16x8*)(u0 + (size_t)(s_base + arow) * NHV + (w * 8 + ahi * 4 + i) * 8);

  if (t < 32) {
    alpha_s[t] = 1.0f;
    fsq_s[t] = fsq[s_base + t];
    tgt_s[t] = tgt[s_base + t];
  }
  __syncthreads();

  for (int it = 0; it < NEWTON_MAX; ++it) {
    {
      const float c2 = 2.0f * alpha_s[arow];
#pragma unroll
      for (int i = 0; i < 4; ++i) {
        const int k8 = w * 8 + ahi * 4 + i;
        const int byte = (arow << 10) + ((k8 ^ (arow & 7)) << 4);
        bf16x8 uv = ureg[i], hf, ef;
#pragma unroll
        for (int q = 0; q < 8; ++q) {
          float u = (float)uv[q];
          float e = __expf(c2 * u);
          float h = (e - 1.0f) * __builtin_amdgcn_rcpf(e + 1.0f);
          hf[q] = (bf16_t)h;
          ef[q] = (bf16_t)(u * (1.0f - h * h));
        }
        *(bf16x8*)((char*)hs + byte) = hf;
        *(bf16x8*)((char*)es + byte) = ef;
      }
    }
    __syncthreads();

    f32x4 accy[2][2] = {};
    f32x4 accw[2][2] = {};
#pragma unroll
    for (int k = 0; k < 16; ++k) {
#pragma unroll
      for (int mt = 0; mt < 2; ++mt) {
        const int row = mt * 16 + la;
        const int byte = (row << 10) + (((k * 4 + lg) ^ (row & 7)) << 4);
        bf16x8 hf = *(const bf16x8*)((const char*)hs + byte);
        bf16x8 ef = *(const bf16x8*)((const char*)es + byte);
#pragma unroll
        for (int nt = 0; nt < 2; ++nt) {
          accy[mt][nt] = __builtin_amdgcn_mfma_f32_16x16x32_bf16(hf, bfr[nt][k], accy[mt][nt], 0, 0, 0);
          accw[mt][nt] = __builtin_amdgcn_mfma_f32_16x16x32_bf16(ef, bfr[nt][k], accw[mt][nt], 0, 0, 0);
        }
      }
    }

#pragma unroll
    for (int mt = 0; mt < 2; ++mt) {
#pragma unroll
      for (int r = 0; r < 4; ++r) {
        float sy = 0.0f, sw = 0.0f;
#pragma unroll
        for (int nt = 0; nt < 2; ++nt) {
          float yv = accy[mt][nt][r], wv = accw[mt][nt][r];
          sy = fmaf(yv, yv, sy);
          sw = fmaf(yv, wv, sw);
        }
        sy += __shfl_xor(sy, 1); sw += __shfl_xor(sw, 1);
        sy += __shfl_xor(sy, 2); sw += __shfl_xor(sw, 2);
        sy += __shfl_xor(sy, 4); sw += __shfl_xor(sw, 4);
        sy += __shfl_xor(sy, 8); sw += __shfl_xor(sw, 8);
        if (la == 0) {
          red[w][mt * 16 + lg * 4 + r][0] = sy;
          red[w][mt * 16 + lg * 4 + r][1] = sw;
        }
      }
    }
    __syncthreads();
    if (t < 32) {
      float SY = 0.0f, SW = 0.0f;
#pragma unroll
      for (int w8 = 0; w8 < 8; ++w8) {
        SY += red[w8][t][0];
        SW += red[w8][t][1];
      }
      float a = alpha_s[t];
      const float fs = fsq_s[t];
      const float V = SY + 0.01f * a * a * fs;
      const float dV = 2.0f * SW + 0.02f * a * fs;
      const float resid = V - tgt_s[t];
      const bool go = resid > RF_TOL;
      if (go) alpha_s[t] = a - resid / dV;
      const int nd = __any(go);
      if (t == 0) notdone_s = nd;
    }
    __syncthreads();
    if (!notdone_s) break;
  }

  {
    const int r = t >> 4;
    const int c4 = t & 15;
    const float a = alpha_s[r];
    const size_t rb = (size_t)(s_base + r) * ND;
    const float4* sp = (const float4*)(fhat + rb);
    float4* dp = (float4*)(out + rb);
#pragma unroll
    for (int jj = 0; jj < 8; ++jj) {
      float4 v = sp[c4 + jj * 16];
      v.x *= a; v.y *= a; v.z *= a; v.w *= a;
      dp[c4 + jj * 16] = v;
    }
  }
}

extern "C" void kernel_launch(void* const* d_in, const int* in_sizes, int n_in,
                              void* d_out, int out_size, void* d_ws, size_t ws_size,
                              hipStream_t stream)
{
  (void)in_sizes; (void)n_in; (void)out_size; (void)ws_size;
  const float* x   = (const float*)d_in[0];
  const float* W1  = (const float*)d_in[1];
  const float* b1  = (const float*)d_in[2];
  const float* W2  = (const float*)d_in[3];
  const float* b2  = (const float*)d_in[4];
  const float* Wv1 = (const float*)d_in[5];
  const float* Wv2 = (const float*)d_in[6];
  float* out = (float*)d_out;

  char* ws = (char*)d_ws;
  size_t off = 0;
  auto alloc = [&](size_t n) { char* p = ws + off; off += (n + 255) & ~(size_t)255; return p; };

  bf16_t* xbf  = (bf16_t*)alloc((size_t)NB * ND * 2);
  bf16_t* w1t  = (bf16_t*)alloc((size_t)NH * ND * 2);
  bf16_t* w2t  = (bf16_t*)alloc((size_t)ND * NH * 2);
  bf16_t* wv1t = (bf16_t*)alloc((size_t)NHV * ND * 2);
  bf16_t* wv2t = (bf16_t*)alloc((size_t)NVO * NHV * 2);
  bf16_t* h1   = (bf16_t*)alloc((size_t)NB * NH * 2);
  float*  fhat = (float*)alloc((size_t)NB * ND * 4);
  bf16_t* fbf  = (bf16_t*)alloc((size_t)NB * ND * 2);
  bf16_t* hx   = (bf16_t*)alloc((size_t)NB * NHV * 2);
  float*  yx   = (float*)alloc((size_t)NB * NVO * 4);
  bf16_t* u0bf = (bf16_t*)alloc((size_t)NB * NHV * 2);
  float*  xsq  = (float*)alloc((size_t)NB * 4);
  float*  fsq  = (float*)alloc((size_t)NB * 4);
  float*  tgt  = (float*)alloc((size_t)NB * 4);

  // 1. fused prep: W1,W2,Wv1,Wv2 transpose+cast (2432 blocks) + x rowcast (2048)
  prep_kernel<<<4480, 256, 0, stream>>>(x, xbf, xsq, W1, w1t, W2, w2t, Wv1, wv1t, Wv2, wv2t);

  // 2. G1: h1 = tanh(x@W1+b1) [16 bx] + hx = tanh(x@Wv1) [4 bx]
  //    256x128 tri-buffer deep-pipe: 20x32 = 640 blocks (640%8==0)
  GJob jh1 { xbf, w1t,  b1,      h1,  nullptr, NH,  ND, NH  / 128, 1 };
  GJob jhx { xbf, wv1t, nullptr, hx,  nullptr, NHV, ND, NHV / 128, 1 };
  gemm_tri_kernel<<<dim3(NH / 128 + NHV / 128, NB / 256), 512, 0, stream>>>(jh1, jhx);

  // 3. G2: fhat = h1@W2+b2 (f32 + bf16 outputs) + yx = hx@Wv2
  //    BM=64: 6x128 = 768 blocks (3/CU)
  GJob jf  { h1,  w2t,  b2,      fbf, fhat,    ND,  NH, ND  / 128, 0 };
  GJob jy  { hx,  wv2t, nullptr, nullptr, yx,  NVO, NHV, NVO / 128, 0 };
  gemm_kernel<64><<<dim3(ND / 128 + NVO / 128, NB / 64), 256, 0, stream>>>(jf, jy);

  // 4. fused post: fsq (from fbf) + target (from yx, xsq)
  post_kernel<<<NB, 128, 0, stream>>>(fbf, yx, xsq, fsq, tgt);

  // 5. G3: u0 = fbf @ Wv1 (bf16 output — newton casts to bf16 anyway)
  GJob ju  { fbf, wv1t, nullptr, u0bf, nullptr, NHV, ND, NHV / 128, 0 };
  gemm_kernel<64><<<dim3(NHV / 128, NB / 64), 256, 0, stream>>>(ju, ju);

  // 6. per-sample masked Newton + fused out = fhat * alpha
  newton_kernel<<<NB / 32, 512, 0, stream>>>(u0bf, wv2t, fsq, tgt, fhat, out);
}

// Round 7
// 124.658 us; speedup vs baseline: 1.1143x; 1.0660x over previous
//
#include <hip/hip_runtime.h>
#include <hip/hip_bf16.h>
#include <stdint.h>
#include <stddef.h>

typedef __bf16 bf16_t;
typedef __bf16 bf16x8 __attribute__((ext_vector_type(8)));
typedef __bf16 bf16x4 __attribute__((ext_vector_type(4)));
typedef float  f32x4  __attribute__((ext_vector_type(4)));

#define NB 8192
#define ND 512
#define NH 2048
#define NHV 512
#define NVO 256
#define RF_TOL 1e-3f
#define NEWTON_MAX 16

typedef const __attribute__((address_space(1))) void gvoid_t;
typedef __attribute__((address_space(3))) void lvoid_t;

__device__ __forceinline__ void gload_lds16(const void* g, void* l) {
  __builtin_amdgcn_global_load_lds((gvoid_t*)g, (lvoid_t*)l, 16, 0, 0);
}

__device__ __forceinline__ float fast_tanhf(float x) {
  x = fminf(fmaxf(x, -15.0f), 15.0f);
  float e = __expf(2.0f * x);
  return (e - 1.0f) * __builtin_amdgcn_rcpf(e + 1.0f);
}

struct GJob {
  const bf16_t* A;    // [8192][K] row-major bf16
  const bf16_t* Bt;   // [N][K] row-major bf16 (pre-transposed B)
  const float*  bias; // [N] or null
  bf16_t* Cbf;        // [8192][N] or null
  float*  Cf;         // [8192][N] or null
  int N, K, nbx, tanh_act;
};

// ---- dual-job GEMM: BMx128 tile, BK=64, single-buffer (m97 structure) ------
// r3-proven config (G1=41us, 525 TF @K=512 — above the m97 ref curve at this
// scale). Three deep-pipeline variants (r1 counted-dbuf, r4/r5 256^2, r6
// tri-buffer) all regressed vs this — scheduling lever closed this session.
template<int BM>
__global__ __launch_bounds__(256, 4)
void gemm_kernel(GJob j0, GJob j1)
{
  constexpr int MI = BM / 32;          // A-frags (16-row) per wave half
  __shared__ bf16_t As[BM * 64];       // BM x 128B
  __shared__ bf16_t Bs[128 * 64];      // 16KB
  const bool first = (int)blockIdx.x < j0.nbx;
  const GJob jb = first ? j0 : j1;
  const int bx = (int)blockIdx.x - (first ? 0 : j0.nbx);
  const int K = jb.K, N = jb.N;

  const int t = threadIdx.x, lane = t & 63, w = t >> 6;
  const int wm = w >> 1, wn = w & 1;
  const int la = lane & 15, lg = lane >> 4;
  const size_t m0 = (size_t)blockIdx.y * BM, n0 = (size_t)bx * 128;

  size_t soffA[MI], soffB[4]; int doff[4];
#pragma unroll
  for (int j = 0; j < 4; ++j) {
    const int off = t * 16 + j * 4096;
    const int r = off >> 7, c = off & 127;
    const size_t so = (size_t)r * K + ((c ^ ((r & 7) << 4)) >> 1);  // pre-swizzled
    if (j < MI) soffA[j] = so;
    soffB[j] = so;
    doff[j] = off;
  }
  const bf16_t* Ab = jb.A + m0 * K;
  const bf16_t* Bb = jb.Bt + n0 * K;

  int abyte[MI][2], bbyte[4][2];
#pragma unroll
  for (int ks = 0; ks < 2; ++ks) {
#pragma unroll
    for (int i = 0; i < MI; ++i) {
      const int ra = wm * (BM / 2) + i * 16 + la;
      abyte[i][ks] = ra * 128 + ((ks * 64 + lg * 16) ^ ((ra & 7) << 4));
    }
#pragma unroll
    for (int j = 0; j < 4; ++j) {
      const int rb = wn * 64 + j * 16 + la;
      bbyte[j][ks] = rb * 128 + ((ks * 64 + lg * 16) ^ ((rb & 7) << 4));
    }
  }

  f32x4 acc[MI][4] = {};
  const int nsteps = K >> 6;

  for (int ts = 0; ts < nsteps; ++ts) {
    const int k0 = ts << 6;
#pragma unroll
    for (int j = 0; j < MI; ++j)
      gload_lds16(Ab + soffA[j] + k0, (char*)As + doff[j]);
#pragma unroll
    for (int j = 0; j < 4; ++j)
      gload_lds16(Bb + soffB[j] + k0, (char*)Bs + doff[j]);
    __syncthreads();

    bf16x8 afr[MI][2], bfr[4][2];
#pragma unroll
    for (int ks = 0; ks < 2; ++ks) {
#pragma unroll
      for (int i = 0; i < MI; ++i)
        afr[i][ks] = *(const bf16x8*)((const char*)As + abyte[i][ks]);
#pragma unroll
      for (int j = 0; j < 4; ++j)
        bfr[j][ks] = *(const bf16x8*)((const char*)Bs + bbyte[j][ks]);
    }
#pragma unroll
    for (int ks = 0; ks < 2; ++ks)
#pragma unroll
      for (int i = 0; i < MI; ++i)
#pragma unroll
        for (int j = 0; j < 4; ++j)
          acc[i][j] = __builtin_amdgcn_mfma_f32_16x16x32_bf16(afr[i][ks], bfr[j][ks], acc[i][j], 0, 0, 0);
    __syncthreads();
  }

#pragma unroll
  for (int i = 0; i < MI; ++i) {
#pragma unroll
    for (int j = 0; j < 4; ++j) {
      const size_t col = n0 + wn * 64 + j * 16 + la;
      const float bv = jb.bias ? jb.bias[col] : 0.0f;
#pragma unroll
      for (int r = 0; r < 4; ++r) {
        const size_t row = m0 + wm * (BM / 2) + i * 16 + lg * 4 + r;
        float v = acc[i][j][r] + bv;
        if (jb.tanh_act) v = fast_tanhf(v);
        if (jb.Cbf) jb.Cbf[row * N + col] = (bf16_t)v;
        if (jb.Cf)  jb.Cf [row * N + col] = v;
      }
    }
  }
}

// ------------------ fused prep: 4 transposes + rowcast(x) -------------------
__device__ __forceinline__ void tr_body(const float* __restrict__ src, bf16_t* __restrict__ dst,
                                        int R, int C, int bidx, float (*tile)[33]) {
  const int tilesx = C >> 5;
  const int bi = (bidx / tilesx) << 5, bj = (bidx % tilesx) << 5;
  const int t = threadIdx.x, tx = t & 31, ty = t >> 5;
#pragma unroll
  for (int r = ty; r < 32; r += 8)
    tile[r][tx] = src[(size_t)(bi + r) * C + (bj + tx)];
  __syncthreads();
#pragma unroll
  for (int r = ty; r < 32; r += 8)
    dst[(size_t)(bj + r) * R + (bi + tx)] = (bf16_t)tile[tx][r];
}

__global__ void prep_kernel(const float* __restrict__ x, bf16_t* __restrict__ xbf, float* __restrict__ xsq,
                            const float* __restrict__ W1, bf16_t* __restrict__ w1t,
                            const float* __restrict__ W2, bf16_t* __restrict__ w2t,
                            const float* __restrict__ Wv1, bf16_t* __restrict__ wv1t,
                            const float* __restrict__ Wv2, bf16_t* __restrict__ wv2t)
{
  __shared__ float tile[32][33];
  const int b = blockIdx.x;
  if (b < 1024)      tr_body(W1, w1t, 512, 2048, b, tile);
  else if (b < 2048) tr_body(W2, w2t, 2048, 512, b - 1024, tile);
  else if (b < 2304) tr_body(Wv1, wv1t, 512, 512, b - 2048, tile);
  else if (b < 2432) tr_body(Wv2, wv2t, 512, 256, b - 2304, tile);
  else {
    const int t = threadIdx.x;
    const int row = (b - 2432) * 4 + (t >> 6), l = t & 63;
    const float4* sr = (const float4*)(x + (size_t)row * ND);
    bf16x4* dw = (bf16x4*)(xbf + (size_t)row * ND);
    float s = 0.0f;
#pragma unroll
    for (int c = l; c < ND / 4; c += 64) {
      float4 v = sr[c];
      s = fmaf(v.x, v.x, fmaf(v.y, v.y, fmaf(v.z, v.z, fmaf(v.w, v.w, s))));
      bf16x4 o;
      o[0] = (bf16_t)v.x; o[1] = (bf16_t)v.y; o[2] = (bf16_t)v.z; o[3] = (bf16_t)v.w;
      dw[c] = o;
    }
#pragma unroll
    for (int m = 32; m; m >>= 1) s += __shfl_xor(s, m);
    if (l == 0) xsq[row] = s;
  }
}

// ------------- fused Newton: u0-GEMM + fsq/tgt + root-find + scale ----------
// Replaces G3 + post + newton + (already-fused) scale. Per block: 32 samples.
//  P0 : fbf[32x512] -> hs in the SAME XOR [row][k8] layout phase-B reads;
//       fsq = rowsumsq(fbf) on the way. tgt from yx + xsq.
//  P1 : u0 = fbf @ Wv1 (MFMA; A from hs, B streamed from L2-resident wv1t).
//  P2 : u0 C-frags -> es in the [row][k8] XOR layout -> ureg register load.
//  Then the proven iterate loop (phase A/B) unchanged.
__global__ __launch_bounds__(512, 1)
void newton_kernel(const bf16_t* __restrict__ fbf, const bf16_t* __restrict__ wv1t,
                   const bf16_t* __restrict__ Wv2t,
                   const float* __restrict__ yx, const float* __restrict__ xsq,
                   const float* __restrict__ fhat, float* __restrict__ out)
{
  __shared__ alignas(16) bf16_t hs[32 * 512];   // 32KB, XOR-swizzled
  __shared__ alignas(16) bf16_t es[32 * 512];
  __shared__ float red[8][32][2];
  __shared__ float alpha_s[32], fsq_s[32], tgt_s[32];
  __shared__ int notdone_s;

  const int t = threadIdx.x, lane = t & 63, w = t >> 6;
  const int la = lane & 15, lg = lane >> 4;
  const int s_base = blockIdx.x * 32;
  const int arow = lane & 31, ahi = lane >> 5;

  // ---- P0: fbf -> hs (swizzled) + fsq; 16 threads per row
  {
    const int row = t >> 4, c0 = (t & 15) * 4;
    float s = 0.0f;
#pragma unroll
    for (int i = 0; i < 4; ++i) {
      const int k8 = c0 + i;
      bf16x8 v = *(const bf16x8*)(fbf + (size_t)(s_base + row) * ND + k8 * 8);
#pragma unroll
      for (int q = 0; q < 8; ++q) { float f = (float)v[q]; s = fmaf(f, f, s); }
      *(bf16x8*)((char*)hs + (row << 10) + ((k8 ^ (row & 7)) << 4)) = v;
    }
    s += __shfl_xor(s, 1); s += __shfl_xor(s, 2); s += __shfl_xor(s, 4); s += __shfl_xor(s, 8);
    if ((t & 15) == 0) fsq_s[row] = s;
  }
  // ---- P0b: tgt = 0.99*(sumsq(yx) + 0.01*xsq); 16 threads per sample
  {
    const int smp = t >> 4;
    const float4* yp = (const float4*)(yx + (size_t)(s_base + smp) * NVO + (t & 15) * 16);
    float s = 0.0f;
#pragma unroll
    for (int i = 0; i < 4; ++i) {
      float4 v = yp[i];
      s = fmaf(v.x, v.x, fmaf(v.y, v.y, fmaf(v.z, v.z, fmaf(v.w, v.w, s))));
    }
    s += __shfl_xor(s, 1); s += __shfl_xor(s, 2); s += __shfl_xor(s, 4); s += __shfl_xor(s, 8);
    if ((t & 15) == 0) tgt_s[smp] = 0.99f * (s + 0.01f * xsq[s_base + smp]);
  }
  if (t < 32) alpha_s[t] = 1.0f;
  __syncthreads();

  // ---- P1: u0 = fbf @ Wv1; wave w owns HV cols [w*64, w*64+64)
  f32x4 uacc[2][4] = {};   // [mt][nt]
#pragma unroll
  for (int k = 0; k < 16; ++k) {
    bf16x8 afr[2];
#pragma unroll
    for (int mt = 0; mt < 2; ++mt) {
      const int row = mt * 16 + la;
      afr[mt] = *(const bf16x8*)((const char*)hs + (row << 10) + (((k * 4 + lg) ^ (row & 7)) << 4));
    }
#pragma unroll
    for (int nt = 0; nt < 4; ++nt) {
      const bf16x8 b = *(const bf16x8*)(wv1t + (size_t)(w * 64 + nt * 16 + la) * ND + k * 32 + lg * 8);
#pragma unroll
      for (int mt = 0; mt < 2; ++mt)
        uacc[mt][nt] = __builtin_amdgcn_mfma_f32_16x16x32_bf16(afr[mt], b, uacc[mt][nt], 0, 0, 0);
    }
  }

  // ---- P2: deposit u0 -> es in [row][k8] XOR layout (C: col=la, row=lg*4+r)
#pragma unroll
  for (int mt = 0; mt < 2; ++mt)
#pragma unroll
    for (int nt = 0; nt < 4; ++nt)
#pragma unroll
      for (int r = 0; r < 4; ++r) {
        const int row = mt * 16 + lg * 4 + r;
        const int col = w * 64 + nt * 16 + la;
        *(bf16_t*)((char*)es + (row << 10) + (((col >> 3) ^ (row & 7)) << 4) + (col & 7) * 2)
            = (bf16_t)uacc[mt][nt][r];
      }
  __syncthreads();

  // ureg from es (phase-A ownership: row=arow, chunks k8 = w*8+ahi*4+i)
  bf16x8 ureg[4];
#pragma unroll
  for (int i = 0; i < 4; ++i) {
    const int k8 = w * 8 + ahi * 4 + i;
    ureg[i] = *(const bf16x8*)((const char*)es + (arow << 10) + ((k8 ^ (arow & 7)) << 4));
  }

  // Wv2t B-frags -> registers (after u0 phase to keep peak VGPR low)
  bf16x8 bfr[2][16];
#pragma unroll
  for (int nt = 0; nt < 2; ++nt) {
    const bf16_t* bp = Wv2t + (size_t)(w * 32 + nt * 16 + la) * NHV + lg * 8;
#pragma unroll
    for (int k = 0; k < 16; ++k)
      bfr[nt][k] = *(const bf16x8*)(bp + k * 32);
  }
  __syncthreads();   // all ureg reads of es done before phase-A overwrites it

  for (int it = 0; it < NEWTON_MAX; ++it) {
    // ---- phase A: tanh from registers -> swizzled LDS
    {
      const float c2 = 2.0f * alpha_s[arow];
#pragma unroll
      for (int i = 0; i < 4; ++i) {
        const int k8 = w * 8 + ahi * 4 + i;
        const int byte = (arow << 10) + ((k8 ^ (arow & 7)) << 4);
        bf16x8 uv = ureg[i], hf, ef;
#pragma unroll
        for (int q = 0; q < 8; ++q) {
          float u = (float)uv[q];
          float e = __expf(c2 * u);
          float h = (e - 1.0f) * __builtin_amdgcn_rcpf(e + 1.0f);
          hf[q] = (bf16_t)h;
          ef[q] = (bf16_t)(u * (1.0f - h * h));
        }
        *(bf16x8*)((char*)hs + byte) = hf;
        *(bf16x8*)((char*)es + byte) = ef;
      }
    }
    __syncthreads();

    // ---- phase B: MFMA with register-resident B
    f32x4 accy[2][2] = {};
    f32x4 accw[2][2] = {};
#pragma unroll
    for (int k = 0; k < 16; ++k) {
#pragma unroll
      for (int mt = 0; mt < 2; ++mt) {
        const int row = mt * 16 + la;
        const int byte = (row << 10) + (((k * 4 + lg) ^ (row & 7)) << 4);
        bf16x8 hf = *(const bf16x8*)((const char*)hs + byte);
        bf16x8 ef = *(const bf16x8*)((const char*)es + byte);
#pragma unroll
        for (int nt = 0; nt < 2; ++nt) {
          accy[mt][nt] = __builtin_amdgcn_mfma_f32_16x16x32_bf16(hf, bfr[nt][k], accy[mt][nt], 0, 0, 0);
          accw[mt][nt] = __builtin_amdgcn_mfma_f32_16x16x32_bf16(ef, bfr[nt][k], accw[mt][nt], 0, 0, 0);
        }
      }
    }

    // ---- reduce: SY = sum y^2, SW = sum y*w  (C layout: col=la, row=lg*4+r)
#pragma unroll
    for (int mt = 0; mt < 2; ++mt) {
#pragma unroll
      for (int r = 0; r < 4; ++r) {
        float sy = 0.0f, sw = 0.0f;
#pragma unroll
        for (int nt = 0; nt < 2; ++nt) {
          float yv = accy[mt][nt][r], wv = accw[mt][nt][r];
          sy = fmaf(yv, yv, sy);
          sw = fmaf(yv, wv, sw);
        }
        sy += __shfl_xor(sy, 1); sw += __shfl_xor(sw, 1);
        sy += __shfl_xor(sy, 2); sw += __shfl_xor(sw, 2);
        sy += __shfl_xor(sy, 4); sw += __shfl_xor(sw, 4);
        sy += __shfl_xor(sy, 8); sw += __shfl_xor(sw, 8);
        if (la == 0) {
          red[w][mt * 16 + lg * 4 + r][0] = sy;
          red[w][mt * 16 + lg * 4 + r][1] = sw;
        }
      }
    }
    __syncthreads();
    if (t < 32) {
      float SY = 0.0f, SW = 0.0f;
#pragma unroll
      for (int w8 = 0; w8 < 8; ++w8) {
        SY += red[w8][t][0];
        SW += red[w8][t][1];
      }
      float a = alpha_s[t];
      const float fs = fsq_s[t];
      const float V = SY + 0.01f * a * a * fs;
      const float dV = 2.0f * SW + 0.02f * a * fs;
      const float resid = V - tgt_s[t];
      const bool go = resid > RF_TOL;
      if (go) alpha_s[t] = a - resid / dV;   // ref's masked Newton step
      const int nd = __any(go);
      if (t == 0) notdone_s = nd;
    }
    __syncthreads();
    if (!notdone_s) break;                   // all converged: further iters no-op
  }

  // ---- fused scale: out = fhat * alpha for this block's 32 rows
  {
    const int r = t >> 4;
    const int c4 = t & 15;
    const float a = alpha_s[r];
    const size_t rb = (size_t)(s_base + r) * ND;
    const float4* sp = (const float4*)(fhat + rb);
    float4* dp = (float4*)(out + rb);
#pragma unroll
    for (int jj = 0; jj < 8; ++jj) {
      float4 v = sp[c4 + jj * 16];
      v.x *= a; v.y *= a; v.z *= a; v.w *= a;
      dp[c4 + jj * 16] = v;
    }
  }
}

extern "C" void kernel_launch(void* const* d_in, const int* in_sizes, int n_in,
                              void* d_out, int out_size, void* d_ws, size_t ws_size,
                              hipStream_t stream)
{
  (void)in_sizes; (void)n_in; (void)out_size; (void)ws_size;
  const float* x   = (const float*)d_in[0];
  const float* W1  = (const float*)d_in[1];
  const float* b1  = (const float*)d_in[2];
  const float* W2  = (const float*)d_in[3];
  const float* b2  = (const float*)d_in[4];
  const float* Wv1 = (const float*)d_in[5];
  const float* Wv2 = (const float*)d_in[6];
  float* out = (float*)d_out;

  char* ws = (char*)d_ws;
  size_t off = 0;
  auto alloc = [&](size_t n) { char* p = ws + off; off += (n + 255) & ~(size_t)255; return p; };

  bf16_t* xbf  = (bf16_t*)alloc((size_t)NB * ND * 2);
  bf16_t* w1t  = (bf16_t*)alloc((size_t)NH * ND * 2);
  bf16_t* w2t  = (bf16_t*)alloc((size_t)ND * NH * 2);
  bf16_t* wv1t = (bf16_t*)alloc((size_t)NHV * ND * 2);
  bf16_t* wv2t = (bf16_t*)alloc((size_t)NVO * NHV * 2);
  bf16_t* h1   = (bf16_t*)alloc((size_t)NB * NH * 2);
  float*  fhat = (float*)alloc((size_t)NB * ND * 4);
  bf16_t* fbf  = (bf16_t*)alloc((size_t)NB * ND * 2);
  bf16_t* hx   = (bf16_t*)alloc((size_t)NB * NHV * 2);
  float*  yx   = (float*)alloc((size_t)NB * NVO * 4);
  float*  xsq  = (float*)alloc((size_t)NB * 4);

  // 1. fused prep: W1,W2,Wv1,Wv2 transpose+cast (2432 blocks) + x rowcast (2048)
  prep_kernel<<<4480, 256, 0, stream>>>(x, xbf, xsq, W1, w1t, W2, w2t, Wv1, wv1t, Wv2, wv2t);

  // 2. G1: h1 = tanh(x@W1+b1) [16 bx] + hx = tanh(x@Wv1) [4 bx]
  //    BM=128: 20x64 = 1280 blocks (r3-proven, 41us)
  GJob jh1 { xbf, w1t,  b1,      h1,  nullptr, NH,  ND, NH  / 128, 1 };
  GJob jhx { xbf, wv1t, nullptr, hx,  nullptr, NHV, ND, NHV / 128, 1 };
  gemm_kernel<128><<<dim3(NH / 128 + NHV / 128, NB / 128), 256, 0, stream>>>(jh1, jhx);

  // 3. G2: fhat = h1@W2+b2 (f32 + bf16 outputs) + yx = hx@Wv2
  //    BM=64: 6x128 = 768 blocks (3/CU)
  GJob jf  { h1,  w2t,  b2,      fbf, fhat,    ND,  NH, ND  / 128, 0 };
  GJob jy  { hx,  wv2t, nullptr, nullptr, yx,  NVO, NHV, NVO / 128, 0 };
  gemm_kernel<64><<<dim3(ND / 128 + NVO / 128, NB / 64), 256, 0, stream>>>(jf, jy);

  // 4. fused Newton: u0-GEMM (ex-G3) + fsq/tgt (ex-post) + root-find + scale
  newton_kernel<<<NB / 32, 512, 0, stream>>>(fbf, wv1t, wv2t, yx, xsq, fhat, out);
}

// Round 8
// 120.307 us; speedup vs baseline: 1.1546x; 1.0362x over previous
//
#include <hip/hip_runtime.h>
#include <hip/hip_bf16.h>
#include <stdint.h>
#include <stddef.h>

typedef __bf16 bf16_t;
typedef __bf16 bf16x8 __attribute__((ext_vector_type(8)));
typedef __bf16 bf16x4 __attribute__((ext_vector_type(4)));
typedef float  f32x4  __attribute__((ext_vector_type(4)));

#define NB 8192
#define ND 512
#define NH 2048
#define NHV 512
#define NVO 256
#define RF_TOL 1e-3f
#define NEWTON_MAX 16

typedef const __attribute__((address_space(1))) void gvoid_t;
typedef __attribute__((address_space(3))) void lvoid_t;

__device__ __forceinline__ void gload_lds16(const void* g, void* l) {
  __builtin_amdgcn_global_load_lds((gvoid_t*)g, (lvoid_t*)l, 16, 0, 0);
}

__device__ __forceinline__ float fast_tanhf(float x) {
  x = fminf(fmaxf(x, -15.0f), 15.0f);
  float e = __expf(2.0f * x);
  return (e - 1.0f) * __builtin_amdgcn_rcpf(e + 1.0f);
}

struct GJob {
  const bf16_t* A;    // [8192][K] row-major bf16
  const bf16_t* Bt;   // [N][K] row-major bf16 (pre-transposed B)
  const float*  bias; // [N] or null
  bf16_t* Cbf;        // [8192][N] or null
  float*  Cf;         // [8192][N] or null
  int N, K, nbx, tanh_act;
};

// ---- dual-job GEMM: BMx128 tile, BK=64, single-buffer (m97 structure) ------
// r3/r7-proven loop. NEW (r8): XCD-aware bijective block swizzle (T1) — grid
// totals divisible by 8. Default block order round-robins same-by blocks
// (which share a 128-row A-panel) across XCDs -> every XCD refetches every
// panel from HBM (G1 FETCH 38MB vs 10.5 ideal). After remap, each XCD owns a
// contiguous (by,bx) run: A-panels + full weight matrix fit its 4MB L2, so
// staging loads become L2 hits (~200cy) instead of HBM misses (~900cy) —
// which is the exposed latency in this single-buffer structure.
template<int BM, bool SWZ>
__global__ __launch_bounds__(256, 4)
void gemm_kernel(GJob j0, GJob j1)
{
  constexpr int MI = BM / 32;          // A-frags (16-row) per wave half
  __shared__ bf16_t As[BM * 64];       // BM x 128B
  __shared__ bf16_t Bs[128 * 64];      // 16KB

  int bx0, by;
  if (SWZ) {
    int f = (int)blockIdx.y * (int)gridDim.x + (int)blockIdx.x;
    const int nwg = (int)gridDim.x * (int)gridDim.y;   // divisible by 8
    f = (f & 7) * (nwg >> 3) + (f >> 3);
    bx0 = f % (int)gridDim.x;
    by  = f / (int)gridDim.x;
  } else {
    bx0 = (int)blockIdx.x;
    by  = (int)blockIdx.y;
  }

  const bool first = bx0 < j0.nbx;
  const GJob jb = first ? j0 : j1;
  const int bx = bx0 - (first ? 0 : j0.nbx);
  const int K = jb.K, N = jb.N;

  const int t = threadIdx.x, lane = t & 63, w = t >> 6;
  const int wm = w >> 1, wn = w & 1;
  const int la = lane & 15, lg = lane >> 4;
  const size_t m0 = (size_t)by * BM, n0 = (size_t)bx * 128;

  size_t soffA[MI], soffB[4]; int doff[4];
#pragma unroll
  for (int j = 0; j < 4; ++j) {
    const int off = t * 16 + j * 4096;
    const int r = off >> 7, c = off & 127;
    const size_t so = (size_t)r * K + ((c ^ ((r & 7) << 4)) >> 1);  // pre-swizzled
    if (j < MI) soffA[j] = so;
    soffB[j] = so;
    doff[j] = off;
  }
  const bf16_t* Ab = jb.A + m0 * K;
  const bf16_t* Bb = jb.Bt + n0 * K;

  int abyte[MI][2], bbyte[4][2];
#pragma unroll
  for (int ks = 0; ks < 2; ++ks) {
#pragma unroll
    for (int i = 0; i < MI; ++i) {
      const int ra = wm * (BM / 2) + i * 16 + la;
      abyte[i][ks] = ra * 128 + ((ks * 64 + lg * 16) ^ ((ra & 7) << 4));
    }
#pragma unroll
    for (int j = 0; j < 4; ++j) {
      const int rb = wn * 64 + j * 16 + la;
      bbyte[j][ks] = rb * 128 + ((ks * 64 + lg * 16) ^ ((rb & 7) << 4));
    }
  }

  f32x4 acc[MI][4] = {};
  const int nsteps = K >> 6;

  for (int ts = 0; ts < nsteps; ++ts) {
    const int k0 = ts << 6;
#pragma unroll
    for (int j = 0; j < MI; ++j)
      gload_lds16(Ab + soffA[j] + k0, (char*)As + doff[j]);
#pragma unroll
    for (int j = 0; j < 4; ++j)
      gload_lds16(Bb + soffB[j] + k0, (char*)Bs + doff[j]);
    __syncthreads();

    bf16x8 afr[MI][2], bfr[4][2];
#pragma unroll
    for (int ks = 0; ks < 2; ++ks) {
#pragma unroll
      for (int i = 0; i < MI; ++i)
        afr[i][ks] = *(const bf16x8*)((const char*)As + abyte[i][ks]);
#pragma unroll
      for (int j = 0; j < 4; ++j)
        bfr[j][ks] = *(const bf16x8*)((const char*)Bs + bbyte[j][ks]);
    }
#pragma unroll
    for (int ks = 0; ks < 2; ++ks)
#pragma unroll
      for (int i = 0; i < MI; ++i)
#pragma unroll
        for (int j = 0; j < 4; ++j)
          acc[i][j] = __builtin_amdgcn_mfma_f32_16x16x32_bf16(afr[i][ks], bfr[j][ks], acc[i][j], 0, 0, 0);
    __syncthreads();
  }

#pragma unroll
  for (int i = 0; i < MI; ++i) {
#pragma unroll
    for (int j = 0; j < 4; ++j) {
      const size_t col = n0 + wn * 64 + j * 16 + la;
      const float bv = jb.bias ? jb.bias[col] : 0.0f;
#pragma unroll
      for (int r = 0; r < 4; ++r) {
        const size_t row = m0 + wm * (BM / 2) + i * 16 + lg * 4 + r;
        float v = acc[i][j][r] + bv;
        if (jb.tanh_act) v = fast_tanhf(v);
        if (jb.Cbf) jb.Cbf[row * N + col] = (bf16_t)v;
        if (jb.Cf)  jb.Cf [row * N + col] = v;
      }
    }
  }
}

// ------------------ fused prep: 4 transposes + rowcast(x) -------------------
__device__ __forceinline__ void tr_body(const float* __restrict__ src, bf16_t* __restrict__ dst,
                                        int R, int C, int bidx, float (*tile)[33]) {
  const int tilesx = C >> 5;
  const int bi = (bidx / tilesx) << 5, bj = (bidx % tilesx) << 5;
  const int t = threadIdx.x, tx = t & 31, ty = t >> 5;
#pragma unroll
  for (int r = ty; r < 32; r += 8)
    tile[r][tx] = src[(size_t)(bi + r) * C + (bj + tx)];
  __syncthreads();
#pragma unroll
  for (int r = ty; r < 32; r += 8)
    dst[(size_t)(bj + r) * R + (bi + tx)] = (bf16_t)tile[tx][r];
}

__global__ void prep_kernel(const float* __restrict__ x, bf16_t* __restrict__ xbf, float* __restrict__ xsq,
                            const float* __restrict__ W1, bf16_t* __restrict__ w1t,
                            const float* __restrict__ W2, bf16_t* __restrict__ w2t,
                            const float* __restrict__ Wv1, bf16_t* __restrict__ wv1t,
                            const float* __restrict__ Wv2, bf16_t* __restrict__ wv2t)
{
  __shared__ float tile[32][33];
  const int b = blockIdx.x;
  if (b < 1024)      tr_body(W1, w1t, 512, 2048, b, tile);
  else if (b < 2048) tr_body(W2, w2t, 2048, 512, b - 1024, tile);
  else if (b < 2304) tr_body(Wv1, wv1t, 512, 512, b - 2048, tile);
  else if (b < 2432) tr_body(Wv2, wv2t, 512, 256, b - 2304, tile);
  else {
    const int t = threadIdx.x;
    const int row = (b - 2432) * 4 + (t >> 6), l = t & 63;
    const float4* sr = (const float4*)(x + (size_t)row * ND);
    bf16x4* dw = (bf16x4*)(xbf + (size_t)row * ND);
    float s = 0.0f;
#pragma unroll
    for (int c = l; c < ND / 4; c += 64) {
      float4 v = sr[c];
      s = fmaf(v.x, v.x, fmaf(v.y, v.y, fmaf(v.z, v.z, fmaf(v.w, v.w, s))));
      bf16x4 o;
      o[0] = (bf16_t)v.x; o[1] = (bf16_t)v.y; o[2] = (bf16_t)v.z; o[3] = (bf16_t)v.w;
      dw[c] = o;
    }
#pragma unroll
    for (int m = 32; m; m >>= 1) s += __shfl_xor(s, m);
    if (l == 0) xsq[row] = s;
  }
}

// ------------- fused Newton: u0-GEMM + fsq/tgt + root-find + scale ----------
__global__ __launch_bounds__(512, 1)
void newton_kernel(const bf16_t* __restrict__ fbf, const bf16_t* __restrict__ wv1t,
                   const bf16_t* __restrict__ Wv2t,
                   const float* __restrict__ yx, const float* __restrict__ xsq,
                   const float* __restrict__ fhat, float* __restrict__ out)
{
  __shared__ alignas(16) bf16_t hs[32 * 512];   // 32KB, XOR-swizzled
  __shared__ alignas(16) bf16_t es[32 * 512];
  __shared__ float red[8][32][2];
  __shared__ float alpha_s[32], fsq_s[32], tgt_s[32];
  __shared__ int notdone_s;

  const int t = threadIdx.x, lane = t & 63, w = t >> 6;
  const int la = lane & 15, lg = lane >> 4;
  const int s_base = blockIdx.x * 32;
  const int arow = lane & 31, ahi = lane >> 5;

  // ---- P0: fbf -> hs (swizzled) + fsq; 16 threads per row
  {
    const int row = t >> 4, c0 = (t & 15) * 4;
    float s = 0.0f;
#pragma unroll
    for (int i = 0; i < 4; ++i) {
      const int k8 = c0 + i;
      bf16x8 v = *(const bf16x8*)(fbf + (size_t)(s_base + row) * ND + k8 * 8);
#pragma unroll
      for (int q = 0; q < 8; ++q) { float f = (float)v[q]; s = fmaf(f, f, s); }
      *(bf16x8*)((char*)hs + (row << 10) + ((k8 ^ (row & 7)) << 4)) = v;
    }
    s += __shfl_xor(s, 1); s += __shfl_xor(s, 2); s += __shfl_xor(s, 4); s += __shfl_xor(s, 8);
    if ((t & 15) == 0) fsq_s[row] = s;
  }
  // ---- P0b: tgt = 0.99*(sumsq(yx) + 0.01*xsq); 16 threads per sample
  {
    const int smp = t >> 4;
    const float4* yp = (const float4*)(yx + (size_t)(s_base + smp) * NVO + (t & 15) * 16);
    float s = 0.0f;
#pragma unroll
    for (int i = 0; i < 4; ++i) {
      float4 v = yp[i];
      s = fmaf(v.x, v.x, fmaf(v.y, v.y, fmaf(v.z, v.z, fmaf(v.w, v.w, s))));
    }
    s += __shfl_xor(s, 1); s += __shfl_xor(s, 2); s += __shfl_xor(s, 4); s += __shfl_xor(s, 8);
    if ((t & 15) == 0) tgt_s[smp] = 0.99f * (s + 0.01f * xsq[s_base + smp]);
  }
  if (t < 32) alpha_s[t] = 1.0f;
  __syncthreads();

  // ---- P1: u0 = fbf @ Wv1; wave w owns HV cols [w*64, w*64+64)
  f32x4 uacc[2][4] = {};   // [mt][nt]
#pragma unroll
  for (int k = 0; k < 16; ++k) {
    bf16x8 afr[2];
#pragma unroll
    for (int mt = 0; mt < 2; ++mt) {
      const int row = mt * 16 + la;
      afr[mt] = *(const bf16x8*)((const char*)hs + (row << 10) + (((k * 4 + lg) ^ (row & 7)) << 4));
    }
#pragma unroll
    for (int nt = 0; nt < 4; ++nt) {
      const bf16x8 b = *(const bf16x8*)(wv1t + (size_t)(w * 64 + nt * 16 + la) * ND + k * 32 + lg * 8);
#pragma unroll
      for (int mt = 0; mt < 2; ++mt)
        uacc[mt][nt] = __builtin_amdgcn_mfma_f32_16x16x32_bf16(afr[mt], b, uacc[mt][nt], 0, 0, 0);
    }
  }

  // ---- P2: deposit u0 -> es in [row][k8] XOR layout (C: col=la, row=lg*4+r)
#pragma unroll
  for (int mt = 0; mt < 2; ++mt)
#pragma unroll
    for (int nt = 0; nt < 4; ++nt)
#pragma unroll
      for (int r = 0; r < 4; ++r) {
        const int row = mt * 16 + lg * 4 + r;
        const int col = w * 64 + nt * 16 + la;
        *(bf16_t*)((char*)es + (row << 10) + (((col >> 3) ^ (row & 7)) << 4) + (col & 7) * 2)
            = (bf16_t)uacc[mt][nt][r];
      }
  __syncthreads();

  // ureg from es (phase-A ownership: row=arow, chunks k8 = w*8+ahi*4+i)
  bf16x8 ureg[4];
#pragma unroll
  for (int i = 0; i < 4; ++i) {
    const int k8 = w * 8 + ahi * 4 + i;
    ureg[i] = *(const bf16x8*)((const char*)es + (arow << 10) + ((k8 ^ (arow & 7)) << 4));
  }

  // Wv2t B-frags -> registers (after u0 phase to keep peak VGPR low)
  bf16x8 bfr[2][16];
#pragma unroll
  for (int nt = 0; nt < 2; ++nt) {
    const bf16_t* bp = Wv2t + (size_t)(w * 32 + nt * 16 + la) * NHV + lg * 8;
#pragma unroll
    for (int k = 0; k < 16; ++k)
      bfr[nt][k] = *(const bf16x8*)(bp + k * 32);
  }
  __syncthreads();   // all ureg reads of es done before phase-A overwrites it

  for (int it = 0; it < NEWTON_MAX; ++it) {
    // ---- phase A: tanh from registers -> swizzled LDS
    {
      const float c2 = 2.0f * alpha_s[arow];
#pragma unroll
      for (int i = 0; i < 4; ++i) {
        const int k8 = w * 8 + ahi * 4 + i;
        const int byte = (arow << 10) + ((k8 ^ (arow & 7)) << 4);
        bf16x8 uv = ureg[i], hf, ef;
#pragma unroll
        for (int q = 0; q < 8; ++q) {
          float u = (float)uv[q];
          float e = __expf(c2 * u);
          float h = (e - 1.0f) * __builtin_amdgcn_rcpf(e + 1.0f);
          hf[q] = (bf16_t)h;
          ef[q] = (bf16_t)(u * (1.0f - h * h));
        }
        *(bf16x8*)((char*)hs + byte) = hf;
        *(bf16x8*)((char*)es + byte) = ef;
      }
    }
    __syncthreads();

    // ---- phase B: MFMA with register-resident B
    f32x4 accy[2][2] = {};
    f32x4 accw[2][2] = {};
#pragma unroll
    for (int k = 0; k < 16; ++k) {
#pragma unroll
      for (int mt = 0; mt < 2; ++mt) {
        const int row = mt * 16 + la;
        const int byte = (row << 10) + (((k * 4 + lg) ^ (row & 7)) << 4);
        bf16x8 hf = *(const bf16x8*)((const char*)hs + byte);
        bf16x8 ef = *(const bf16x8*)((const char*)es + byte);
#pragma unroll
        for (int nt = 0; nt < 2; ++nt) {
          accy[mt][nt] = __builtin_amdgcn_mfma_f32_16x16x32_bf16(hf, bfr[nt][k], accy[mt][nt], 0, 0, 0);
          accw[mt][nt] = __builtin_amdgcn_mfma_f32_16x16x32_bf16(ef, bfr[nt][k], accw[mt][nt], 0, 0, 0);
        }
      }
    }

    // ---- reduce: SY = sum y^2, SW = sum y*w  (C layout: col=la, row=lg*4+r)
#pragma unroll
    for (int mt = 0; mt < 2; ++mt) {
#pragma unroll
      for (int r = 0; r < 4; ++r) {
        float sy = 0.0f, sw = 0.0f;
#pragma unroll
        for (int nt = 0; nt < 2; ++nt) {
          float yv = accy[mt][nt][r], wv = accw[mt][nt][r];
          sy = fmaf(yv, yv, sy);
          sw = fmaf(yv, wv, sw);
        }
        sy += __shfl_xor(sy, 1); sw += __shfl_xor(sw, 1);
        sy += __shfl_xor(sy, 2); sw += __shfl_xor(sw, 2);
        sy += __shfl_xor(sy, 4); sw += __shfl_xor(sw, 4);
        sy += __shfl_xor(sy, 8); sw += __shfl_xor(sw, 8);
        if (la == 0) {
          red[w][mt * 16 + lg * 4 + r][0] = sy;
          red[w][mt * 16 + lg * 4 + r][1] = sw;
        }
      }
    }
    __syncthreads();
    if (t < 32) {
      float SY = 0.0f, SW = 0.0f;
#pragma unroll
      for (int w8 = 0; w8 < 8; ++w8) {
        SY += red[w8][t][0];
        SW += red[w8][t][1];
      }
      float a = alpha_s[t];
      const float fs = fsq_s[t];
      const float V = SY + 0.01f * a * a * fs;
      const float dV = 2.0f * SW + 0.02f * a * fs;
      const float resid = V - tgt_s[t];
      const bool go = resid > RF_TOL;
      if (go) alpha_s[t] = a - resid / dV;   // ref's masked Newton step
      const int nd = __any(go);
      if (t == 0) notdone_s = nd;
    }
    __syncthreads();
    if (!notdone_s) break;                   // all converged: further iters no-op
  }

  // ---- fused scale: out = fhat * alpha for this block's 32 rows
  {
    const int r = t >> 4;
    const int c4 = t & 15;
    const float a = alpha_s[r];
    const size_t rb = (size_t)(s_base + r) * ND;
    const float4* sp = (const float4*)(fhat + rb);
    float4* dp = (float4*)(out + rb);
#pragma unroll
    for (int jj = 0; jj < 8; ++jj) {
      float4 v = sp[c4 + jj * 16];
      v.x *= a; v.y *= a; v.z *= a; v.w *= a;
      dp[c4 + jj * 16] = v;
    }
  }
}

extern "C" void kernel_launch(void* const* d_in, const int* in_sizes, int n_in,
                              void* d_out, int out_size, void* d_ws, size_t ws_size,
                              hipStream_t stream)
{
  (void)in_sizes; (void)n_in; (void)out_size; (void)ws_size;
  const float* x   = (const float*)d_in[0];
  const float* W1  = (const float*)d_in[1];
  const float* b1  = (const float*)d_in[2];
  const float* W2  = (const float*)d_in[3];
  const float* b2  = (const float*)d_in[4];
  const float* Wv1 = (const float*)d_in[5];
  const float* Wv2 = (const float*)d_in[6];
  float* out = (float*)d_out;

  char* ws = (char*)d_ws;
  size_t off = 0;
  auto alloc = [&](size_t n) { char* p = ws + off; off += (n + 255) & ~(size_t)255; return p; };

  bf16_t* xbf  = (bf16_t*)alloc((size_t)NB * ND * 2);
  bf16_t* w1t  = (bf16_t*)alloc((size_t)NH * ND * 2);
  bf16_t* w2t  = (bf16_t*)alloc((size_t)ND * NH * 2);
  bf16_t* wv1t = (bf16_t*)alloc((size_t)NHV * ND * 2);
  bf16_t* wv2t = (bf16_t*)alloc((size_t)NVO * NHV * 2);
  bf16_t* h1   = (bf16_t*)alloc((size_t)NB * NH * 2);
  float*  fhat = (float*)alloc((size_t)NB * ND * 4);
  bf16_t* fbf  = (bf16_t*)alloc((size_t)NB * ND * 2);
  bf16_t* hx   = (bf16_t*)alloc((size_t)NB * NHV * 2);
  float*  yx   = (float*)alloc((size_t)NB * NVO * 4);
  float*  xsq  = (float*)alloc((size_t)NB * 4);

  // 1. fused prep: W1,W2,Wv1,Wv2 transpose+cast (2432 blocks) + x rowcast (2048)
  prep_kernel<<<4480, 256, 0, stream>>>(x, xbf, xsq, W1, w1t, W2, w2t, Wv1, wv1t, Wv2, wv2t);

  // 2. G1: h1 = tanh(x@W1+b1) [16 bx] + hx = tanh(x@Wv1) [4 bx]
  //    BM=128: 20x64 = 1280 blocks (%8==0 -> bijective XCD swizzle)
  GJob jh1 { xbf, w1t,  b1,      h1,  nullptr, NH,  ND, NH  / 128, 1 };
  GJob jhx { xbf, wv1t, nullptr, hx,  nullptr, NHV, ND, NHV / 128, 1 };
  gemm_kernel<128, true><<<dim3(NH / 128 + NHV / 128, NB / 128), 256, 0, stream>>>(jh1, jhx);

  // 3. G2: fhat = h1@W2+b2 (f32 + bf16 outputs) + yx = hx@Wv2
  //    BM=64: 6x128 = 768 blocks (%8==0 -> bijective XCD swizzle)
  GJob jf  { h1,  w2t,  b2,      fbf, fhat,    ND,  NH, ND  / 128, 0 };
  GJob jy  { hx,  wv2t, nullptr, nullptr, yx,  NVO, NHV, NVO / 128, 0 };
  gemm_kernel<64, true><<<dim3(ND / 128 + NVO / 128, NB / 64), 256, 0, stream>>>(jf, jy);

  // 4. fused Newton: u0-GEMM (ex-G3) + fsq/tgt (ex-post) + root-find + scale
  newton_kernel<<<NB / 32, 512, 0, stream>>>(fbf, wv1t, wv2t, yx, xsq, fhat, out);
}

// Round 9
// 115.286 us; speedup vs baseline: 1.2049x; 1.0436x over previous
//
#include <hip/hip_runtime.h>
#include <hip/hip_bf16.h>
#include <stdint.h>
#include <stddef.h>

typedef __bf16 bf16_t;
typedef __bf16 bf16x8 __attribute__((ext_vector_type(8)));
typedef __bf16 bf16x4 __attribute__((ext_vector_type(4)));
typedef float  f32x4  __attribute__((ext_vector_type(4)));

#define NB 8192
#define ND 512
#define NH 2048
#define NHV 512
#define NVO 256
#define RF_TOL 1e-3f
#define NEWTON_MAX 16

typedef const __attribute__((address_space(1))) void gvoid_t;
typedef __attribute__((address_space(3))) void lvoid_t;

__device__ __forceinline__ void gload_lds16(const void* g, void* l) {
  __builtin_amdgcn_global_load_lds((gvoid_t*)g, (lvoid_t*)l, 16, 0, 0);
}

__device__ __forceinline__ float fast_tanhf(float x) {
  x = fminf(fmaxf(x, -15.0f), 15.0f);
  float e = __expf(2.0f * x);
  return (e - 1.0f) * __builtin_amdgcn_rcpf(e + 1.0f);
}

struct GJob {
  const bf16_t* A;    // [8192][K] row-major bf16
  const bf16_t* Bt;   // [N][K] row-major bf16 (pre-transposed B)
  const float*  bias; // [N] or null
  bf16_t* Cbf;        // [8192][N] or null
  float*  Cf;         // [8192][N] or null
  float*  rowsq;      // [8192] or null: atomicAdd per-row sum(v^2) (no C write)
  int N, K, nbx, tanh_act;
};

// ------------------ transpose tile body (shared w/ prep) --------------------
__device__ __forceinline__ void tr_body(const float* __restrict__ src, bf16_t* __restrict__ dst,
                                        int R, int C, int bidx, float (*tile)[33]) {
  const int tilesx = C >> 5;
  const int bi = (bidx / tilesx) << 5, bj = (bidx % tilesx) << 5;
  const int t = threadIdx.x, tx = t & 31, ty = t >> 5;
#pragma unroll
  for (int r = ty; r < 32; r += 8)
    tile[r][tx] = src[(size_t)(bi + r) * C + (bj + tx)];
  __syncthreads();
#pragma unroll
  for (int r = ty; r < 32; r += 8)
    dst[(size_t)(bj + r) * R + (bi + tx)] = (bf16_t)tile[tx][r];
}

// ---- dual-job GEMM: BMx128 tile, BK=64, single-buffer (m97 structure) ------
// r3/r7/r8-proven loop + XCD swizzle (r8: FETCH 38->25MB). GEMM-loop lever
// closed (r8 decision rule: FETCH dropped, dur didn't -> structure-saturated).
// NEW (r9): TBX>0 reserves bx columns [TBX, gridDim.x) for W2/Wv2 transpose
// blocks (moved out of prep; they backfill G1's occupancy tail). rowsq jobs
// (jy) skip the C write and atomicAdd per-row sum(v^2) instead (kills the
// 16MB yx round-trip; buffer zeroed by prep).
template<int BM, bool SWZ, int TBX>
__global__ __launch_bounds__(256, 4)
void gemm_kernel(GJob j0, GJob j1,
                 const float* tw2, bf16_t* tw2t, const float* twv2, bf16_t* twv2t)
{
  constexpr int MI = BM / 32;          // A-frags (16-row) per wave half
  __shared__ bf16_t As[BM * 64];       // BM x 128B
  __shared__ bf16_t Bs[128 * 64];      // 16KB

  int bx0, by;
  if (SWZ) {
    int f = (int)blockIdx.y * (int)gridDim.x + (int)blockIdx.x;
    const int nwg = (int)gridDim.x * (int)gridDim.y;   // divisible by 8
    f = (f & 7) * (nwg >> 3) + (f >> 3);
    bx0 = f % (int)gridDim.x;
    by  = f / (int)gridDim.x;
  } else {
    bx0 = (int)blockIdx.x;
    by  = (int)blockIdx.y;
  }

  if (TBX > 0 && bx0 >= TBX) {         // transpose freeloader blocks (G1 only)
    float (*tile)[33] = reinterpret_cast<float(*)[33]>(As);
    const int idx = (bx0 - TBX) * (int)gridDim.y + by;   // [0, 1152)
    if (idx < 1024) tr_body(tw2, tw2t, 2048, 512, idx, tile);
    else            tr_body(twv2, twv2t, 512, 256, idx - 1024, tile);
    return;
  }

  const bool first = bx0 < j0.nbx;
  const GJob jb = first ? j0 : j1;
  const int bx = bx0 - (first ? 0 : j0.nbx);
  const int K = jb.K, N = jb.N;

  const int t = threadIdx.x, lane = t & 63, w = t >> 6;
  const int wm = w >> 1, wn = w & 1;
  const int la = lane & 15, lg = lane >> 4;
  const size_t m0 = (size_t)by * BM, n0 = (size_t)bx * 128;

  size_t soffA[MI], soffB[4]; int doff[4];
#pragma unroll
  for (int j = 0; j < 4; ++j) {
    const int off = t * 16 + j * 4096;
    const int r = off >> 7, c = off & 127;
    const size_t so = (size_t)r * K + ((c ^ ((r & 7) << 4)) >> 1);  // pre-swizzled
    if (j < MI) soffA[j] = so;
    soffB[j] = so;
    doff[j] = off;
  }
  const bf16_t* Ab = jb.A + m0 * K;
  const bf16_t* Bb = jb.Bt + n0 * K;

  int abyte[MI][2], bbyte[4][2];
#pragma unroll
  for (int ks = 0; ks < 2; ++ks) {
#pragma unroll
    for (int i = 0; i < MI; ++i) {
      const int ra = wm * (BM / 2) + i * 16 + la;
      abyte[i][ks] = ra * 128 + ((ks * 64 + lg * 16) ^ ((ra & 7) << 4));
    }
#pragma unroll
    for (int j = 0; j < 4; ++j) {
      const int rb = wn * 64 + j * 16 + la;
      bbyte[j][ks] = rb * 128 + ((ks * 64 + lg * 16) ^ ((rb & 7) << 4));
    }
  }

  f32x4 acc[MI][4] = {};
  const int nsteps = K >> 6;

  for (int ts = 0; ts < nsteps; ++ts) {
    const int k0 = ts << 6;
#pragma unroll
    for (int j = 0; j < MI; ++j)
      gload_lds16(Ab + soffA[j] + k0, (char*)As + doff[j]);
#pragma unroll
    for (int j = 0; j < 4; ++j)
      gload_lds16(Bb + soffB[j] + k0, (char*)Bs + doff[j]);
    __syncthreads();

    bf16x8 afr[MI][2], bfr[4][2];
#pragma unroll
    for (int ks = 0; ks < 2; ++ks) {
#pragma unroll
      for (int i = 0; i < MI; ++i)
        afr[i][ks] = *(const bf16x8*)((const char*)As + abyte[i][ks]);
#pragma unroll
      for (int j = 0; j < 4; ++j)
        bfr[j][ks] = *(const bf16x8*)((const char*)Bs + bbyte[j][ks]);
    }
#pragma unroll
    for (int ks = 0; ks < 2; ++ks)
#pragma unroll
      for (int i = 0; i < MI; ++i)
#pragma unroll
        for (int j = 0; j < 4; ++j)
          acc[i][j] = __builtin_amdgcn_mfma_f32_16x16x32_bf16(afr[i][ks], bfr[j][ks], acc[i][j], 0, 0, 0);
    __syncthreads();
  }

  // epilogue (runtime flags; all uniform branches)
  if (jb.rowsq) {
    // per-row sum(v^2) over this block's 128 cols (64/wave-half), atomicAdd
#pragma unroll
    for (int i = 0; i < MI; ++i) {
#pragma unroll
      for (int r = 0; r < 4; ++r) {
        float s = 0.0f;
#pragma unroll
        for (int j = 0; j < 4; ++j) { float v = acc[i][j][r]; s = fmaf(v, v, s); }
        s += __shfl_xor(s, 1); s += __shfl_xor(s, 2);
        s += __shfl_xor(s, 4); s += __shfl_xor(s, 8);
        if (la == 0)
          atomicAdd(&jb.rowsq[m0 + wm * (BM / 2) + i * 16 + lg * 4 + r], s);
      }
    }
    return;
  }
#pragma unroll
  for (int i = 0; i < MI; ++i) {
#pragma unroll
    for (int j = 0; j < 4; ++j) {
      const size_t col = n0 + wn * 64 + j * 16 + la;
      const float bv = jb.bias ? jb.bias[col] : 0.0f;
#pragma unroll
      for (int r = 0; r < 4; ++r) {
        const size_t row = m0 + wm * (BM / 2) + i * 16 + lg * 4 + r;
        float v = acc[i][j][r] + bv;
        if (jb.tanh_act) v = fast_tanhf(v);
        if (jb.Cbf) jb.Cbf[row * N + col] = (bf16_t)v;
        if (jb.Cf)  jb.Cf [row * N + col] = v;
      }
    }
  }
}

// ------ fused prep: W1,Wv1 transposes + rowcast(x) + zero yxsq --------------
// (W2/Wv2 transposes moved into G1's launch as freeloader blocks.)
__global__ void prep_kernel(const float* __restrict__ x, bf16_t* __restrict__ xbf, float* __restrict__ xsq,
                            const float* __restrict__ W1, bf16_t* __restrict__ w1t,
                            const float* __restrict__ Wv1, bf16_t* __restrict__ wv1t,
                            float* __restrict__ yxsq)
{
  __shared__ float tile[32][33];
  const int b = blockIdx.x;
  if (b < 1024)      tr_body(W1, w1t, 512, 2048, b, tile);
  else if (b < 1280) tr_body(Wv1, wv1t, 512, 512, b - 1024, tile);
  else {
    const int t = threadIdx.x;
    const int row = (b - 1280) * 4 + (t >> 6), l = t & 63;
    const float4* sr = (const float4*)(x + (size_t)row * ND);
    bf16x4* dw = (bf16x4*)(xbf + (size_t)row * ND);
    float s = 0.0f;
#pragma unroll
    for (int c = l; c < ND / 4; c += 64) {
      float4 v = sr[c];
      s = fmaf(v.x, v.x, fmaf(v.y, v.y, fmaf(v.z, v.z, fmaf(v.w, v.w, s))));
      bf16x4 o;
      o[0] = (bf16_t)v.x; o[1] = (bf16_t)v.y; o[2] = (bf16_t)v.z; o[3] = (bf16_t)v.w;
      dw[c] = o;
    }
#pragma unroll
    for (int m = 32; m; m >>= 1) s += __shfl_xor(s, m);
    if (l == 0) xsq[row] = s;
    if (l == 1) yxsq[row] = 0.0f;   // zero the G2 sumsq accumulator
  }
}

// ------------- fused Newton: u0-GEMM + fsq/tgt + root-find + scale ----------
__global__ __launch_bounds__(512, 1)
void newton_kernel(const bf16_t* __restrict__ fbf, const bf16_t* __restrict__ wv1t,
                   const bf16_t* __restrict__ Wv2t,
                   const float* __restrict__ yxsq, const float* __restrict__ xsq,
                   const float* __restrict__ fhat, float* __restrict__ out)
{
  __shared__ alignas(16) bf16_t hs[32 * 512];   // 32KB, XOR-swizzled
  __shared__ alignas(16) bf16_t es[32 * 512];
  __shared__ float red[8][32][2];
  __shared__ float alpha_s[32], fsq_s[32], tgt_s[32];
  __shared__ int notdone_s;

  const int t = threadIdx.x, lane = t & 63, w = t >> 6;
  const int la = lane & 15, lg = lane >> 4;
  const int s_base = blockIdx.x * 32;
  const int arow = lane & 31, ahi = lane >> 5;

  // ---- P0: fbf -> hs (swizzled) + fsq; 16 threads per row
  {
    const int row = t >> 4, c0 = (t & 15) * 4;
    float s = 0.0f;
#pragma unroll
    for (int i = 0; i < 4; ++i) {
      const int k8 = c0 + i;
      bf16x8 v = *(const bf16x8*)(fbf + (size_t)(s_base + row) * ND + k8 * 8);
#pragma unroll
      for (int q = 0; q < 8; ++q) { float f = (float)v[q]; s = fmaf(f, f, s); }
      *(bf16x8*)((char*)hs + (row << 10) + ((k8 ^ (row & 7)) << 4)) = v;
    }
    s += __shfl_xor(s, 1); s += __shfl_xor(s, 2); s += __shfl_xor(s, 4); s += __shfl_xor(s, 8);
    if ((t & 15) == 0) fsq_s[row] = s;
  }
  if (t < 32) {
    alpha_s[t] = 1.0f;
    tgt_s[t] = 0.99f * (yxsq[s_base + t] + 0.01f * xsq[s_base + t]);
  }
  __syncthreads();

  // ---- P1: u0 = fbf @ Wv1; wave w owns HV cols [w*64, w*64+64)
  f32x4 uacc[2][4] = {};   // [mt][nt]
#pragma unroll
  for (int k = 0; k < 16; ++k) {
    bf16x8 afr[2];
#pragma unroll
    for (int mt = 0; mt < 2; ++mt) {
      const int row = mt * 16 + la;
      afr[mt] = *(const bf16x8*)((const char*)hs + (row << 10) + (((k * 4 + lg) ^ (row & 7)) << 4));
    }
#pragma unroll
    for (int nt = 0; nt < 4; ++nt) {
      const bf16x8 b = *(const bf16x8*)(wv1t + (size_t)(w * 64 + nt * 16 + la) * ND + k * 32 + lg * 8);
#pragma unroll
      for (int mt = 0; mt < 2; ++mt)
        uacc[mt][nt] = __builtin_amdgcn_mfma_f32_16x16x32_bf16(afr[mt], b, uacc[mt][nt], 0, 0, 0);
    }
  }

  // ---- P2: deposit u0 -> es in [row][k8] XOR layout (C: col=la, row=lg*4+r)
#pragma unroll
  for (int mt = 0; mt < 2; ++mt)
#pragma unroll
    for (int nt = 0; nt < 4; ++nt)
#pragma unroll
      for (int r = 0; r < 4; ++r) {
        const int row = mt * 16 + lg * 4 + r;
        const int col = w * 64 + nt * 16 + la;
        *(bf16_t*)((char*)es + (row << 10) + (((col >> 3) ^ (row & 7)) << 4) + (col & 7) * 2)
            = (bf16_t)uacc[mt][nt][r];
      }
  __syncthreads();

  // ureg from es (phase-A ownership: row=arow, chunks k8 = w*8+ahi*4+i)
  bf16x8 ureg[4];
#pragma unroll
  for (int i = 0; i < 4; ++i) {
    const int k8 = w * 8 + ahi * 4 + i;
    ureg[i] = *(const bf16x8*)((const char*)es + (arow << 10) + ((k8 ^ (arow & 7)) << 4));
  }

  // Wv2t B-frags -> registers (after u0 phase to keep peak VGPR low)
  bf16x8 bfr[2][16];
#pragma unroll
  for (int nt = 0; nt < 2; ++nt) {
    const bf16_t* bp = Wv2t + (size_t)(w * 32 + nt * 16 + la) * NHV + lg * 8;
#pragma unroll
    for (int k = 0; k < 16; ++k)
      bfr[nt][k] = *(const bf16x8*)(bp + k * 32);
  }
  __syncthreads();   // all ureg reads of es done before phase-A overwrites it

  for (int it = 0; it < NEWTON_MAX; ++it) {
    // ---- phase A: tanh from registers -> swizzled LDS
    {
      const float c2 = 2.0f * alpha_s[arow];
#pragma unroll
      for (int i = 0; i < 4; ++i) {
        const int k8 = w * 8 + ahi * 4 + i;
        const int byte = (arow << 10) + ((k8 ^ (arow & 7)) << 4);
        bf16x8 uv = ureg[i], hf, ef;
#pragma unroll
        for (int q = 0; q < 8; ++q) {
          float u = (float)uv[q];
          float e = __expf(c2 * u);
          float h = (e - 1.0f) * __builtin_amdgcn_rcpf(e + 1.0f);
          hf[q] = (bf16_t)h;
          ef[q] = (bf16_t)(u * (1.0f - h * h));
        }
        *(bf16x8*)((char*)hs + byte) = hf;
        *(bf16x8*)((char*)es + byte) = ef;
      }
    }
    __syncthreads();

    // ---- phase B: MFMA with register-resident B
    f32x4 accy[2][2] = {};
    f32x4 accw[2][2] = {};
#pragma unroll
    for (int k = 0; k < 16; ++k) {
#pragma unroll
      for (int mt = 0; mt < 2; ++mt) {
        const int row = mt * 16 + la;
        const int byte = (row << 10) + (((k * 4 + lg) ^ (row & 7)) << 4);
        bf16x8 hf = *(const bf16x8*)((const char*)hs + byte);
        bf16x8 ef = *(const bf16x8*)((const char*)es + byte);
#pragma unroll
        for (int nt = 0; nt < 2; ++nt) {
          accy[mt][nt] = __builtin_amdgcn_mfma_f32_16x16x32_bf16(hf, bfr[nt][k], accy[mt][nt], 0, 0, 0);
          accw[mt][nt] = __builtin_amdgcn_mfma_f32_16x16x32_bf16(ef, bfr[nt][k], accw[mt][nt], 0, 0, 0);
        }
      }
    }

    // ---- reduce: SY = sum y^2, SW = sum y*w  (C layout: col=la, row=lg*4+r)
#pragma unroll
    for (int mt = 0; mt < 2; ++mt) {
#pragma unroll
      for (int r = 0; r < 4; ++r) {
        float sy = 0.0f, sw = 0.0f;
#pragma unroll
        for (int nt = 0; nt < 2; ++nt) {
          float yv = accy[mt][nt][r], wv = accw[mt][nt][r];
          sy = fmaf(yv, yv, sy);
          sw = fmaf(yv, wv, sw);
        }
        sy += __shfl_xor(sy, 1); sw += __shfl_xor(sw, 1);
        sy += __shfl_xor(sy, 2); sw += __shfl_xor(sw, 2);
        sy += __shfl_xor(sy, 4); sw += __shfl_xor(sw, 4);
        sy += __shfl_xor(sy, 8); sw += __shfl_xor(sw, 8);
        if (la == 0) {
          red[w][mt * 16 + lg * 4 + r][0] = sy;
          red[w][mt * 16 + lg * 4 + r][1] = sw;
        }
      }
    }
    __syncthreads();
    if (t < 32) {
      float SY = 0.0f, SW = 0.0f;
#pragma unroll
      for (int w8 = 0; w8 < 8; ++w8) {
        SY += red[w8][t][0];
        SW += red[w8][t][1];
      }
      float a = alpha_s[t];
      const float fs = fsq_s[t];
      const float V = SY + 0.01f * a * a * fs;
      const float dV = 2.0f * SW + 0.02f * a * fs;
      const float resid = V - tgt_s[t];
      const bool go = resid > RF_TOL;
      if (go) alpha_s[t] = a - resid / dV;   // ref's masked Newton step
      const int nd = __any(go);
      if (t == 0) notdone_s = nd;
    }
    __syncthreads();
    if (!notdone_s) break;                   // all converged: further iters no-op
  }

  // ---- fused scale: out = fhat * alpha for this block's 32 rows
  {
    const int r = t >> 4;
    const int c4 = t & 15;
    const float a = alpha_s[r];
    const size_t rb = (size_t)(s_base + r) * ND;
    const float4* sp = (const float4*)(fhat + rb);
    float4* dp = (float4*)(out + rb);
#pragma unroll
    for (int jj = 0; jj < 8; ++jj) {
      float4 v = sp[c4 + jj * 16];
      v.x *= a; v.y *= a; v.z *= a; v.w *= a;
      dp[c4 + jj * 16] = v;
    }
  }
}

extern "C" void kernel_launch(void* const* d_in, const int* in_sizes, int n_in,
                              void* d_out, int out_size, void* d_ws, size_t ws_size,
                              hipStream_t stream)
{
  (void)in_sizes; (void)n_in; (void)out_size; (void)ws_size;
  const float* x   = (const float*)d_in[0];
  const float* W1  = (const float*)d_in[1];
  const float* b1  = (const float*)d_in[2];
  const float* W2  = (const float*)d_in[3];
  const float* b2  = (const float*)d_in[4];
  const float* Wv1 = (const float*)d_in[5];
  const float* Wv2 = (const float*)d_in[6];
  float* out = (float*)d_out;

  char* ws = (char*)d_ws;
  size_t off = 0;
  auto alloc = [&](size_t n) { char* p = ws + off; off += (n + 255) & ~(size_t)255; return p; };

  bf16_t* xbf  = (bf16_t*)alloc((size_t)NB * ND * 2);
  bf16_t* w1t  = (bf16_t*)alloc((size_t)NH * ND * 2);
  bf16_t* w2t  = (bf16_t*)alloc((size_t)ND * NH * 2);
  bf16_t* wv1t = (bf16_t*)alloc((size_t)NHV * ND * 2);
  bf16_t* wv2t = (bf16_t*)alloc((size_t)NVO * NHV * 2);
  bf16_t* h1   = (bf16_t*)alloc((size_t)NB * NH * 2);
  float*  fhat = (float*)alloc((size_t)NB * ND * 4);
  bf16_t* fbf  = (bf16_t*)alloc((size_t)NB * ND * 2);
  bf16_t* hx   = (bf16_t*)alloc((size_t)NB * NHV * 2);
  float*  xsq  = (float*)alloc((size_t)NB * 4);
  float*  yxsq = (float*)alloc((size_t)NB * 4);

  // 1. prep: W1,Wv1 transpose+cast (1280 blocks) + x rowcast + yxsq zero (2048)
  prep_kernel<<<3328, 256, 0, stream>>>(x, xbf, xsq, W1, w1t, Wv1, wv1t, yxsq);

  // 2. G1: h1 = tanh(x@W1+b1) [16 bx] + hx = tanh(x@Wv1) [4 bx]
  //    + 18 bx columns of W2/Wv2 transpose freeloaders (1152 blocks)
  //    grid (38, 64) = 2432 blocks, %8==0 -> bijective XCD swizzle
  GJob jh1 { xbf, w1t,  b1,      h1,  nullptr, nullptr, NH,  ND, NH  / 128, 1 };
  GJob jhx { xbf, wv1t, nullptr, hx,  nullptr, nullptr, NHV, ND, NHV / 128, 1 };
  gemm_kernel<128, true, 20><<<dim3(38, NB / 128), 256, 0, stream>>>(jh1, jhx, W2, w2t, Wv2, wv2t);

  // 3. G2: fhat = h1@W2+b2 (f32 + bf16 outputs) + yxsq += rowsumsq(hx@Wv2)
  //    BM=64: 6x128 = 768 blocks (%8==0 -> bijective XCD swizzle)
  GJob jf  { h1,  w2t,  b2,      fbf, fhat,    nullptr, ND,  NH, ND  / 128, 0 };
  GJob jy  { hx,  wv2t, nullptr, nullptr, nullptr, yxsq, NVO, NHV, NVO / 128, 0 };
  gemm_kernel<64, true, 0><<<dim3(ND / 128 + NVO / 128, NB / 64), 256, 0, stream>>>(jf, jy, nullptr, nullptr, nullptr, nullptr);

  // 4. fused Newton: u0-GEMM + fsq/tgt + root-find + scale
  newton_kernel<<<NB / 32, 512, 0, stream>>>(fbf, wv1t, wv2t, yxsq, xsq, fhat, out);
}